// Round 6
// baseline (604.404 us; speedup 1.0000x reference)
//
#include <hip/hip_runtime.h>
#include <hip/hip_bf16.h>
#include <math.h>

// Problem constants (from reference)
#define S_   512
#define B_   32
#define D_   256
#define H_   8
#define DH_  32
#define E_   (H_*(5*DH_+2))   // 1296
#define SB_  (S_*B_)          // 16384
#define LN_EPSF 1e-5f

#define ROWP_ 164             // padded row stride (floats): 164*4=656B, 16B-aligned
#define CH2_  32              // scan chunk (steps)
#define NC2_  (S_/CH2_)       // 16 chunks

// ---------------- reductions ----------------
__device__ __forceinline__ float wave_sum64(float v){
  #pragma unroll
  for (int m = 32; m >= 1; m >>= 1) v += __shfl_xor(v, m, 64);
  return v;
}
__device__ __forceinline__ float gsum32(float v){
  #pragma unroll
  for (int m = 16; m >= 1; m >>= 1) v += __shfl_xor(v, m, 32);
  return v;
}
__device__ __forceinline__ float gmax32(float v){
  #pragma unroll
  for (int m = 16; m >= 1; m >>= 1) v = fmaxf(v, __shfl_xor(v, m, 32));
  return v;
}

// ---------------- global->LDS DMA helpers ----------------
// LDS dest is wave-uniform base + lane*16B; global src is per-lane.
__device__ __forceinline__ void gl16(const float* g, float* l){
  __builtin_amdgcn_global_load_lds(
      (const __attribute__((address_space(1))) unsigned int*)g,
      (__attribute__((address_space(3))) unsigned int*)l, 16, 0, 0);
}
// plane[t][0..31] <- rows gb + t*ROWP_ + fieldOff, t = 0..31  (4 DMA instrs)
__device__ __forceinline__ void stage_plane32(const float* gb, int fieldOff,
                                              float* plane, int lane){
  const int tt = lane >> 3, dd = (lane & 7) << 2;
  #pragma unroll
  for (int i = 0; i < 4; i++)
    gl16(gb + (size_t)(8*i + tt)*ROWP_ + fieldOff + dd, plane + i*256);
}
// bpl[t][0..3] <- gb + t*ROWP_ + 160  (beta,rbeta,pad,pad), t = 0..31
__device__ __forceinline__ void stage_beta32(const float* gb, float* bpl, int lane){
  if (lane < CH2_) gl16(gb + (size_t)lane*ROWP_ + 5*DH_, bpl);
}

// ---------------- LayerNorm: one block per (s,b) row ----------------
__global__ __launch_bounds__(256) void ln_kernel(const float* __restrict__ x,
                                                 const float* __restrict__ g,
                                                 const float* __restrict__ b,
                                                 float* __restrict__ o){
  __shared__ float sbuf[4];
  const int row = blockIdx.x, tid = threadIdx.x;
  const float v = x[(size_t)row*D_ + tid];
  float s = wave_sum64(v);
  if ((tid & 63) == 0) sbuf[tid >> 6] = s;
  __syncthreads();
  const float mu = (sbuf[0]+sbuf[1]+sbuf[2]+sbuf[3]) * (1.f/D_);
  __syncthreads();
  const float d = v - mu;
  float s2 = wave_sum64(d*d);
  if ((tid & 63) == 0) sbuf[tid >> 6] = s2;
  __syncthreads();
  const float var = (sbuf[0]+sbuf[1]+sbuf[2]+sbuf[3]) * (1.f/D_);
  const float rstd = rsqrtf(var + LN_EPSF);
  o[(size_t)row*D_ + tid] = d*rstd*g[tid] + b[tid];
}

// ------- GEMM1 -> transposed padded layout qkvT[pair][s][164] -------
__global__ __launch_bounds__(256) void gemm_qkvT(const float* __restrict__ A,
                                                 const float* __restrict__ Bm,
                                                 float* __restrict__ qkvT,
                                                 int M, int N, int K){
  const int BM=128, BN=128, BK=16;
  __shared__ float As[BK][BM+4];
  __shared__ float Bs[BK][BN+4];
  const int tid = threadIdx.x;
  const int m0 = blockIdx.y*BM, n0 = blockIdx.x*BN;
  const int tx = tid & 15, ty = tid >> 4;
  float acc[8][8];
  #pragma unroll
  for (int i=0;i<8;i++)
    #pragma unroll
    for (int j=0;j<8;j++) acc[i][j]=0.f;

  const int lrow = tid >> 2;
  const int lcol = (tid & 3) << 2;

  for (int k0=0;k0<K;k0+=BK){
    #pragma unroll
    for (int p=0;p<2;p++){
      const int row = lrow + p*64;
      const float4 va = *(const float4*)(A + (size_t)(m0+row)*K + k0 + lcol);
      As[lcol+0][row]=va.x; As[lcol+1][row]=va.y; As[lcol+2][row]=va.z; As[lcol+3][row]=va.w;
      const int nrow = n0 + row;
      float4 vb = make_float4(0.f,0.f,0.f,0.f);
      if (nrow < N) vb = *(const float4*)(Bm + (size_t)nrow*K + k0 + lcol);
      Bs[lcol+0][row]=vb.x; Bs[lcol+1][row]=vb.y; Bs[lcol+2][row]=vb.z; Bs[lcol+3][row]=vb.w;
    }
    __syncthreads();
    #pragma unroll
    for (int k=0;k<BK;k++){
      float a[8], bb[8];
      *(float4*)&a[0]  = *(const float4*)&As[k][ty*8];
      *(float4*)&a[4]  = *(const float4*)&As[k][ty*8+4];
      *(float4*)&bb[0] = *(const float4*)&Bs[k][tx*8];
      *(float4*)&bb[4] = *(const float4*)&Bs[k][tx*8+4];
      #pragma unroll
      for (int i=0;i<8;i++)
        #pragma unroll
        for (int j=0;j<8;j++) acc[i][j] = fmaf(a[i], bb[j], acc[i][j]);
    }
    __syncthreads();
  }
  #pragma unroll
  for (int i=0;i<8;i++){
    const int m = m0 + ty*8 + i;
    const int s = m >> 5, bq = m & 31;
    #pragma unroll
    for (int j=0;j<8;j++){
      const int n = n0 + tx*8 + j;
      if (n < N){
        const unsigned head = (unsigned)n / 162u;
        const unsigned jj   = (unsigned)n - head*162u;
        qkvT[((size_t)(bq*8u+head)*S_ + s)*ROWP_ + jj] = acc[i][j];
      }
    }
  }
}

// ---------------- activations, in-place on qkvT rows ----------------
// row: q(0:32) k(32:64) v(64:96) rk(96:128) rv(128:160) beta(160) rbeta(161)
__global__ __launch_bounds__(256) void act2_kernel(float* __restrict__ qkvT){
  const int row = blockIdx.x*8 + (threadIdx.x >> 5);
  const int i = threadIdx.x & 31;
  float* base = qkvT + (size_t)row*ROWP_;
  float qv  = base[i];
  float kv  = base[DH_ + i];
  float rkv = base[3*DH_ + i];
  qv = qv > 0.f ? qv + 1.f : __expf(qv);   // elu+1
  kv = kv > 0.f ? kv + 1.f : __expf(kv);
  const float qs = gsum32(qv);
  const float ks = gsum32(kv);
  const float rm = gmax32(rkv);
  const float re = __expf(rkv - rm);
  const float rs = gsum32(re);
  base[i]         = qv / qs;
  base[DH_ + i]   = kv / ks;
  base[3*DH_ + i] = re / rs;
  if (i < 2){
    const float bv = base[5*DH_ + i];
    base[5*DH_ + i] = 1.f/(1.f + __expf(-bv));
  }
}

// ---------------- ff scan ----------------
// 256 blocks x 1 wave. Lane (r,p) owns cols p*16..p*16+15 of W row r.
// Inputs DMA-staged per 32-step chunk (double-buffered, vmcnt-counted) ->
// the compiler cannot sink these loads; no per-step global latency.
// z overwrites qkvT's dead q-slot (global store, off critical path).
__global__ __launch_bounds__(64,1) void ff_scan(float* __restrict__ qkvT){
  const int pair = blockIdx.x;
  const int lane = threadIdx.x;
  const int r = lane & 31, p = lane >> 5;
  float* gbase = qkvT + (size_t)pair*S_*ROWP_;

  __shared__ __align__(16) float Lq[2][CH2_][DH_];
  __shared__ __align__(16) float Lk[2][CH2_][DH_];
  __shared__ __align__(16) float Lv[2][CH2_][DH_];
  __shared__ __align__(16) float Lb[2][CH2_][4];

  float W[16];
  #pragma unroll
  for (int i=0;i<16;i++) W[i]=0.f;

  // prologue: stage chunk 0
  stage_plane32(gbase, 0,      &Lq[0][0][0], lane);
  stage_plane32(gbase, DH_,    &Lk[0][0][0], lane);
  stage_plane32(gbase, 2*DH_,  &Lv[0][0][0], lane);
  stage_beta32 (gbase,         &Lb[0][0][0], lane);
  asm volatile("s_waitcnt vmcnt(0)" ::: "memory");

  for (int c = 0; c < NC2_; ++c){
    const int bi = c & 1;
    if (c+1 < NC2_){
      const float* gnext = gbase + (size_t)(c+1)*CH2_*ROWP_;
      stage_plane32(gnext, 0,     &Lq[bi^1][0][0], lane);
      stage_plane32(gnext, DH_,   &Lk[bi^1][0][0], lane);
      stage_plane32(gnext, 2*DH_, &Lv[bi^1][0][0], lane);
      stage_beta32 (gnext,        &Lb[bi^1][0][0], lane);
    }
    float* zrow0 = gbase + (size_t)c*CH2_*ROWP_;
    #pragma unroll 4
    for (int t = 0; t < CH2_; ++t){
      float q[16], k[16];
      #pragma unroll
      for (int j=0;j<4;j++){
        *(float4*)&q[4*j] = *(const float4*)&Lq[bi][t][p*16 + 4*j];
        *(float4*)&k[4*j] = *(const float4*)&Lk[bi][t][p*16 + 4*j];
      }
      const float vv = Lv[bi][t][r];
      const float bb = Lb[bi][t][0];

      // dot1 = W[r, my16] . k16  -> combine across halves
      float a0=0.f,a1=0.f,a2=0.f,a3=0.f;
      #pragma unroll
      for (int c4=0;c4<16;c4+=4){
        a0=fmaf(W[c4+0],k[c4+0],a0); a1=fmaf(W[c4+1],k[c4+1],a1);
        a2=fmaf(W[c4+2],k[c4+2],a2); a3=fmaf(W[c4+3],k[c4+3],a3);
      }
      float dot1 = (a0+a1)+(a2+a3);
      dot1 += __shfl_xor(dot1, 32, 64);
      const float coef = bb*(vv - dot1);

      // update + z-dot interleaved
      float b0=0.f,b1=0.f,b2=0.f,b3=0.f;
      #pragma unroll
      for (int c4=0;c4<16;c4+=4){
        W[c4+0]=fmaf(coef,k[c4+0],W[c4+0]); b0=fmaf(W[c4+0],q[c4+0],b0);
        W[c4+1]=fmaf(coef,k[c4+1],W[c4+1]); b1=fmaf(W[c4+1],q[c4+1],b1);
        W[c4+2]=fmaf(coef,k[c4+2],W[c4+2]); b2=fmaf(W[c4+2],q[c4+2],b2);
        W[c4+3]=fmaf(coef,k[c4+3],W[c4+3]); b3=fmaf(W[c4+3],q[c4+3],b3);
      }
      float z = (b0+b1)+(b2+b3);
      z += __shfl_xor(z, 32, 64);
      if (!p) zrow0[(size_t)t*ROWP_ + r] = z;   // dead q-slot
    }
    asm volatile("s_waitcnt vmcnt(0)" ::: "memory");
  }
}

// ---------------- rec scan ----------------
// Same structure; lane (r,p) owns cols p*16.. of R row r. Serial chain:
// h -> exp -> ebuf write -> 4x broadcast b128 read -> dot2(4-deep) -> shfl
// -> rcp -> fma -> h. R's delta update (h-independent) fills the LDS
// round trip. z comes from ff via the q-slot, staged like any input.
__global__ __launch_bounds__(64,1) void rec_scan(const float* __restrict__ qkvT,
                                                 float* __restrict__ hs){
  const int pair = blockIdx.x;
  const int lane = threadIdx.x;
  const int r = lane & 31, p = lane >> 5;
  const int b = pair >> 3, hh = pair & 7;
  const float* gbase = qkvT + (size_t)pair*S_*ROWP_;

  __shared__ __align__(16) float Lrk[2][CH2_][DH_];
  __shared__ __align__(16) float Lrv[2][CH2_][DH_];
  __shared__ __align__(16) float Lz [2][CH2_][DH_];
  __shared__ __align__(16) float Lb [2][CH2_][4];
  __shared__ __align__(16) float ebuf[2][DH_];

  float R[16];
  #pragma unroll
  for (int i=0;i<16;i++) R[i]=0.f;
  float h = 0.f;

  stage_plane32(gbase, 3*DH_, &Lrk[0][0][0], lane);
  stage_plane32(gbase, 4*DH_, &Lrv[0][0][0], lane);
  stage_plane32(gbase, 0,     &Lz [0][0][0], lane);
  stage_beta32 (gbase,        &Lb [0][0][0], lane);
  asm volatile("s_waitcnt vmcnt(0)" ::: "memory");

  for (int c = 0; c < NC2_; ++c){
    const int bi = c & 1;
    if (c+1 < NC2_){
      const float* gnext = gbase + (size_t)(c+1)*CH2_*ROWP_;
      stage_plane32(gnext, 3*DH_, &Lrk[bi^1][0][0], lane);
      stage_plane32(gnext, 4*DH_, &Lrv[bi^1][0][0], lane);
      stage_plane32(gnext, 0,     &Lz [bi^1][0][0], lane);
      stage_beta32 (gnext,        &Lb [bi^1][0][0], lane);
    }
    const int s0 = c*CH2_;
    #pragma unroll 4
    for (int t = 0; t < CH2_; ++t){
      // ---- h-chain head: publish e = exp(h_prev)
      const float e = __expf(h);
      ebuf[t&1][r] = e;            // both halves write same value (benign)

      float k[16];
      #pragma unroll
      for (int j=0;j<4;j++)
        *(float4*)&k[4*j] = *(const float4*)&Lrk[bi][t][p*16 + 4*j];
      const float vv = Lrv[bi][t][r];
      const float zz = Lz [bi][t][r];
      const float bb = Lb [bi][t][1];

      // ---- R delta update (h-independent; covers the ebuf round trip)
      float a0=0.f,a1=0.f,a2=0.f,a3=0.f;
      #pragma unroll
      for (int c4=0;c4<16;c4+=4){
        a0=fmaf(R[c4+0],k[c4+0],a0); a1=fmaf(R[c4+1],k[c4+1],a1);
        a2=fmaf(R[c4+2],k[c4+2],a2); a3=fmaf(R[c4+3],k[c4+3],a3);
      }
      float dot1 = (a0+a1)+(a2+a3);
      dot1 += __shfl_xor(dot1, 32, 64);
      const float coef = bb*(vv - dot1);
      #pragma unroll
      for (int c4=0;c4<16;c4+=4){
        R[c4+0]=fmaf(coef,k[c4+0],R[c4+0]); R[c4+1]=fmaf(coef,k[c4+1],R[c4+1]);
        R[c4+2]=fmaf(coef,k[c4+2],R[c4+2]); R[c4+3]=fmaf(coef,k[c4+3],R[c4+3]);
      }

      // ---- read this half's 16 e-values (broadcast b128)
      float ev[16];
      #pragma unroll
      for (int j=0;j<4;j++)
        *(float4*)&ev[4*j] = *(const float4*)&ebuf[t&1][p*16 + 4*j];

      // Ssum: local 15-add tree + 1 cross-half combine (off dot2's chain)
      float t0=(ev[0]+ev[1])+(ev[2]+ev[3]),   t1=(ev[4]+ev[5])+(ev[6]+ev[7]);
      float t2=(ev[8]+ev[9])+(ev[10]+ev[11]), t3=(ev[12]+ev[13])+(ev[14]+ev[15]);
      float Ss = (t0+t1)+(t2+t3);
      Ss += __shfl_xor(Ss, 32, 64);

      // dot2 = R_new[r, my16] . e16 -> combine
      float d0=0.f,d1=0.f,d2=0.f,d3=0.f;
      #pragma unroll
      for (int c4=0;c4<16;c4+=4){
        d0=fmaf(R[c4+0],ev[c4+0],d0); d1=fmaf(R[c4+1],ev[c4+1],d1);
        d2=fmaf(R[c4+2],ev[c4+2],d2); d3=fmaf(R[c4+3],ev[c4+3],d3);
      }
      float dot2 = (d0+d1)+(d2+d3);
      dot2 += __shfl_xor(dot2, 32, 64);

      h = fmaf(dot2, __builtin_amdgcn_rcpf(Ss), zz);
      if (!p) hs[((size_t)(s0+t)*B_ + b)*D_ + hh*DH_ + r] = h;
    }
    asm volatile("s_waitcnt vmcnt(0)" ::: "memory");
  }
}

// ---------------- GEMM2 (C = hs . out_W^T + x) ----------------
__global__ __launch_bounds__(256) void gemm_out(const float* __restrict__ A,
                                                const float* __restrict__ Bm,
                                                const float* __restrict__ X,
                                                float* __restrict__ C,
                                                int M, int N, int K){
  const int BM=128, BN=128, BK=16;
  __shared__ float As[BK][BM+4];
  __shared__ float Bs[BK][BN+4];
  const int tid = threadIdx.x;
  const int m0 = blockIdx.y*BM, n0 = blockIdx.x*BN;
  const int tx = tid & 15, ty = tid >> 4;
  float acc[8][8];
  #pragma unroll
  for (int i=0;i<8;i++)
    #pragma unroll
    for (int j=0;j<8;j++) acc[i][j]=0.f;

  const int lrow = tid >> 2;
  const int lcol = (tid & 3) << 2;

  for (int k0=0;k0<K;k0+=BK){
    #pragma unroll
    for (int p=0;p<2;p++){
      const int row = lrow + p*64;
      const float4 va = *(const float4*)(A + (size_t)(m0+row)*K + k0 + lcol);
      As[lcol+0][row]=va.x; As[lcol+1][row]=va.y; As[lcol+2][row]=va.z; As[lcol+3][row]=va.w;
      const float4 vb = *(const float4*)(Bm + (size_t)(n0+row)*K + k0 + lcol);
      Bs[lcol+0][row]=vb.x; Bs[lcol+1][row]=vb.y; Bs[lcol+2][row]=vb.z; Bs[lcol+3][row]=vb.w;
    }
    __syncthreads();
    #pragma unroll
    for (int k=0;k<BK;k++){
      float a[8], bb[8];
      *(float4*)&a[0]  = *(const float4*)&As[k][ty*8];
      *(float4*)&a[4]  = *(const float4*)&As[k][ty*8+4];
      *(float4*)&bb[0] = *(const float4*)&Bs[k][tx*8];
      *(float4*)&bb[4] = *(const float4*)&Bs[k][tx*8+4];
      #pragma unroll
      for (int i=0;i<8;i++)
        #pragma unroll
        for (int j=0;j<8;j++) acc[i][j] = fmaf(a[i], bb[j], acc[i][j]);
    }
    __syncthreads();
  }
  #pragma unroll
  for (int i=0;i<8;i++){
    const size_t m = (size_t)(m0 + ty*8 + i);
    #pragma unroll
    for (int j=0;j<8;j+=4){
      const int n = n0 + tx*8 + j;
      float4 rr = make_float4(acc[i][j],acc[i][j+1],acc[i][j+2],acc[i][j+3]);
      const float4 xv = *(const float4*)(X + m*N + n);
      rr.x+=xv.x; rr.y+=xv.y; rr.z+=xv.z; rr.w+=xv.w;
      *(float4*)(C + m*N + n) = rr;
    }
  }
}

// ---------------- launcher ----------------
extern "C" void kernel_launch(void* const* d_in, const int* in_sizes, int n_in,
                              void* d_out, int out_size, void* d_ws, size_t ws_size,
                              hipStream_t stream) {
  const float* x      = (const float*)d_in[0];
  const float* slow_W = (const float*)d_in[1];
  const float* out_W  = (const float*)d_in[2];
  const float* ln_g   = (const float*)d_in[3];
  const float* ln_b   = (const float*)d_in[4];
  float* out = (float*)d_out;

  float* o    = out;                            // LN out in d_out (overwritten by GEMM2)
  float* qkvT = (float*)d_ws;                   // [256 pairs][512 s][164]  (86MB)
  float* hs   = qkvT + (size_t)B_*H_*S_*ROWP_;  // [SB][D] (16.8MB)

  ln_kernel<<<SB_, 256, 0, stream>>>(x, ln_g, ln_b, o);

  dim3 g1((E_ + 127)/128, SB_/128);             // (11, 128)
  gemm_qkvT<<<g1, 256, 0, stream>>>(o, slow_W, qkvT, SB_, E_, D_);

  act2_kernel<<<B_*H_*S_/8, 256, 0, stream>>>(qkvT);

  ff_scan<<<B_*H_, 64, 0, stream>>>(qkvT);
  rec_scan<<<B_*H_, 64, 0, stream>>>(qkvT, hs);

  dim3 g2(D_/128, SB_/128);                     // (2, 128)
  gemm_out<<<g2, 256, 0, stream>>>(hs, out_W, x, out, SB_, D_, D_);
}

// Round 7
// 545.619 us; speedup vs baseline: 1.1077x; 1.1077x over previous
//
#include <hip/hip_runtime.h>
#include <hip/hip_bf16.h>
#include <math.h>

// Problem constants (from reference)
#define S_   512
#define B_   32
#define D_   256
#define H_   8
#define DH_  32
#define E_   (H_*(5*DH_+2))   // 1296
#define SB_  (S_*B_)          // 16384
#define LN_EPSF 1e-5f

#define ROWP_ 164             // padded row stride (floats): 656B, 16B-aligned
#define CH2_  32              // scan chunk (steps)
#define NC2_  (S_/CH2_)       // 16 chunks

// ---------------- cross-lane helpers ----------------
__device__ __forceinline__ float wave_sum64(float v){
  #pragma unroll
  for (int m = 32; m >= 1; m >>= 1) v += __shfl_xor(v, m, 64);
  return v;
}
__device__ __forceinline__ float gsum32(float v){
  #pragma unroll
  for (int m = 16; m >= 1; m >>= 1) v += __shfl_xor(v, m, 32);
  return v;
}
__device__ __forceinline__ float gmax32(float v){
  #pragma unroll
  for (int m = 16; m >= 1; m >>= 1) v = fmaxf(v, __shfl_xor(v, m, 32));
  return v;
}

// cross-half (lane r <-> lane r+32) SUM via v_permlane32_swap_b32 (VALU,
// ~8 cyc) instead of __shfl_xor's ds_bpermute (~120 cyc at 1 wave/CU).
// permlane32_swap(x,x) returns {p0,p1} with p0 = hi-half broadcast to both
// halves, p1 = lo-half broadcast -> p0+p1 = cross-half sum in every lane.
#if __has_builtin(__builtin_amdgcn_permlane32_swap)
typedef int v2i_ __attribute__((ext_vector_type(2)));
__device__ __forceinline__ float xhalf_sum(float x){
  v2i_ r = __builtin_amdgcn_permlane32_swap(__float_as_int(x), __float_as_int(x), false, false);
  return __int_as_float(r.x) + __int_as_float(r.y);
}
#else
__device__ __forceinline__ float xhalf_sum(float x){
  return x + __shfl_xor(x, 32, 64);
}
#endif

// ---------------- global->LDS DMA helpers ----------------
__device__ __forceinline__ void gl16(const float* g, float* l){
  __builtin_amdgcn_global_load_lds(
      (const __attribute__((address_space(1))) unsigned int*)g,
      (__attribute__((address_space(3))) unsigned int*)l, 16, 0, 0);
}
// plane[t][0..31] <- rows gb + t*ROWP_ + fieldOff, t = 0..31  (4 DMA instrs)
__device__ __forceinline__ void stage_plane32(const float* gb, int fieldOff,
                                              float* plane, int lane){
  const int tt = lane >> 3, dd = (lane & 7) << 2;
  #pragma unroll
  for (int i = 0; i < 4; i++)
    gl16(gb + (size_t)(8*i + tt)*ROWP_ + fieldOff + dd, plane + i*256);
}
// bpl[t][0..3] <- gb + t*ROWP_ + 160  (beta,rbeta,pad,pad), t = 0..31
__device__ __forceinline__ void stage_beta32(const float* gb, float* bpl, int lane){
  if (lane < CH2_) gl16(gb + (size_t)lane*ROWP_ + 5*DH_, bpl);
}

// ---------------- LayerNorm: one block per (s,b) row ----------------
__global__ __launch_bounds__(256) void ln_kernel(const float* __restrict__ x,
                                                 const float* __restrict__ g,
                                                 const float* __restrict__ b,
                                                 float* __restrict__ o){
  __shared__ float sbuf[4];
  const int row = blockIdx.x, tid = threadIdx.x;
  const float v = x[(size_t)row*D_ + tid];
  float s = wave_sum64(v);
  if ((tid & 63) == 0) sbuf[tid >> 6] = s;
  __syncthreads();
  const float mu = (sbuf[0]+sbuf[1]+sbuf[2]+sbuf[3]) * (1.f/D_);
  __syncthreads();
  const float d = v - mu;
  float s2 = wave_sum64(d*d);
  if ((tid & 63) == 0) sbuf[tid >> 6] = s2;
  __syncthreads();
  const float var = (sbuf[0]+sbuf[1]+sbuf[2]+sbuf[3]) * (1.f/D_);
  const float rstd = rsqrtf(var + LN_EPSF);
  o[(size_t)row*D_ + tid] = d*rstd*g[tid] + b[tid];
}

// ------- GEMM1 -> transposed padded layout qkvT[pair][s][164] -------
__global__ __launch_bounds__(256) void gemm_qkvT(const float* __restrict__ A,
                                                 const float* __restrict__ Bm,
                                                 float* __restrict__ qkvT,
                                                 int M, int N, int K){
  const int BM=128, BN=128, BK=16;
  __shared__ float As[BK][BM+4];
  __shared__ float Bs[BK][BN+4];
  const int tid = threadIdx.x;
  const int m0 = blockIdx.y*BM, n0 = blockIdx.x*BN;
  const int tx = tid & 15, ty = tid >> 4;
  float acc[8][8];
  #pragma unroll
  for (int i=0;i<8;i++)
    #pragma unroll
    for (int j=0;j<8;j++) acc[i][j]=0.f;

  const int lrow = tid >> 2;
  const int lcol = (tid & 3) << 2;

  for (int k0=0;k0<K;k0+=BK){
    #pragma unroll
    for (int p=0;p<2;p++){
      const int row = lrow + p*64;
      const float4 va = *(const float4*)(A + (size_t)(m0+row)*K + k0 + lcol);
      As[lcol+0][row]=va.x; As[lcol+1][row]=va.y; As[lcol+2][row]=va.z; As[lcol+3][row]=va.w;
      const int nrow = n0 + row;
      float4 vb = make_float4(0.f,0.f,0.f,0.f);
      if (nrow < N) vb = *(const float4*)(Bm + (size_t)nrow*K + k0 + lcol);
      Bs[lcol+0][row]=vb.x; Bs[lcol+1][row]=vb.y; Bs[lcol+2][row]=vb.z; Bs[lcol+3][row]=vb.w;
    }
    __syncthreads();
    #pragma unroll
    for (int k=0;k<BK;k++){
      float a[8], bb[8];
      *(float4*)&a[0]  = *(const float4*)&As[k][ty*8];
      *(float4*)&a[4]  = *(const float4*)&As[k][ty*8+4];
      *(float4*)&bb[0] = *(const float4*)&Bs[k][tx*8];
      *(float4*)&bb[4] = *(const float4*)&Bs[k][tx*8+4];
      #pragma unroll
      for (int i=0;i<8;i++)
        #pragma unroll
        for (int j=0;j<8;j++) acc[i][j] = fmaf(a[i], bb[j], acc[i][j]);
    }
    __syncthreads();
  }
  #pragma unroll
  for (int i=0;i<8;i++){
    const int m = m0 + ty*8 + i;
    const int s = m >> 5, bq = m & 31;
    #pragma unroll
    for (int j=0;j<8;j++){
      const int n = n0 + tx*8 + j;
      if (n < N){
        const unsigned head = (unsigned)n / 162u;
        const unsigned jj   = (unsigned)n - head*162u;
        qkvT[((size_t)(bq*8u+head)*S_ + s)*ROWP_ + jj] = acc[i][j];
      }
    }
  }
}

// ---------------- activations, in-place on qkvT rows ----------------
// row: q(0:32) k(32:64) v(64:96) rk(96:128) rv(128:160) beta(160) rbeta(161)
__global__ __launch_bounds__(256) void act2_kernel(float* __restrict__ qkvT){
  const int row = blockIdx.x*8 + (threadIdx.x >> 5);
  const int i = threadIdx.x & 31;
  float* base = qkvT + (size_t)row*ROWP_;
  float qv  = base[i];
  float kv  = base[DH_ + i];
  float rkv = base[3*DH_ + i];
  qv = qv > 0.f ? qv + 1.f : __expf(qv);   // elu+1
  kv = kv > 0.f ? kv + 1.f : __expf(kv);
  const float qs = gsum32(qv);
  const float ks = gsum32(kv);
  const float rm = gmax32(rkv);
  const float re = __expf(rkv - rm);
  const float rs = gsum32(re);
  base[i]         = qv / qs;
  base[DH_ + i]   = kv / ks;
  base[3*DH_ + i] = re / rs;
  if (i < 2){
    const float bv = base[5*DH_ + i];
    base[5*DH_ + i] = 1.f/(1.f + __expf(-bv));
  }
}

// ---------------- ff scan ----------------
// 256 blocks x 1 wave. Lane (r,p) owns cols p*16..p*16+15 of W row r.
// Inputs DMA-staged per 32-step chunk (double-buffered). Cross-half combines
// via permlane32_swap (VALU) -> no LDS/ds_bpermute on the serial chain.
__global__ __launch_bounds__(64,1) void ff_scan(float* __restrict__ qkvT){
  const int pair = blockIdx.x;
  const int lane = threadIdx.x;
  const int r = lane & 31, p = lane >> 5;
  float* gbase = qkvT + (size_t)pair*S_*ROWP_;

  __shared__ __align__(16) float Lq[2][CH2_][DH_];
  __shared__ __align__(16) float Lk[2][CH2_][DH_];
  __shared__ __align__(16) float Lv[2][CH2_][DH_];
  __shared__ __align__(16) float Lb[2][CH2_][4];

  float W[16];
  #pragma unroll
  for (int i=0;i<16;i++) W[i]=0.f;

  stage_plane32(gbase, 0,      &Lq[0][0][0], lane);
  stage_plane32(gbase, DH_,    &Lk[0][0][0], lane);
  stage_plane32(gbase, 2*DH_,  &Lv[0][0][0], lane);
  stage_beta32 (gbase,         &Lb[0][0][0], lane);
  asm volatile("s_waitcnt vmcnt(0)" ::: "memory");

  for (int c = 0; c < NC2_; ++c){
    const int bi = c & 1;
    if (c+1 < NC2_){
      const float* gnext = gbase + (size_t)(c+1)*CH2_*ROWP_;
      stage_plane32(gnext, 0,     &Lq[bi^1][0][0], lane);
      stage_plane32(gnext, DH_,   &Lk[bi^1][0][0], lane);
      stage_plane32(gnext, 2*DH_, &Lv[bi^1][0][0], lane);
      stage_beta32 (gnext,        &Lb[bi^1][0][0], lane);
    }
    float* zrow0 = gbase + (size_t)c*CH2_*ROWP_;
    #pragma unroll 4
    for (int t = 0; t < CH2_; ++t){
      float q[16], k[16];
      #pragma unroll
      for (int j=0;j<4;j++){
        *(float4*)&q[4*j] = *(const float4*)&Lq[bi][t][p*16 + 4*j];
        *(float4*)&k[4*j] = *(const float4*)&Lk[bi][t][p*16 + 4*j];
      }
      const float vv = Lv[bi][t][r];
      const float bb = Lb[bi][t][0];

      // dot1 = W[r,:] . k  (local 16 + cross-half VALU combine)
      float a0=0.f,a1=0.f,a2=0.f,a3=0.f;
      #pragma unroll
      for (int c4=0;c4<16;c4+=4){
        a0=fmaf(W[c4+0],k[c4+0],a0); a1=fmaf(W[c4+1],k[c4+1],a1);
        a2=fmaf(W[c4+2],k[c4+2],a2); a3=fmaf(W[c4+3],k[c4+3],a3);
      }
      const float dot1 = xhalf_sum((a0+a1)+(a2+a3));
      const float coef = bb*(vv - dot1);

      // update + z-dot interleaved
      float b0=0.f,b1=0.f,b2=0.f,b3=0.f;
      #pragma unroll
      for (int c4=0;c4<16;c4+=4){
        W[c4+0]=fmaf(coef,k[c4+0],W[c4+0]); b0=fmaf(W[c4+0],q[c4+0],b0);
        W[c4+1]=fmaf(coef,k[c4+1],W[c4+1]); b1=fmaf(W[c4+1],q[c4+1],b1);
        W[c4+2]=fmaf(coef,k[c4+2],W[c4+2]); b2=fmaf(W[c4+2],q[c4+2],b2);
        W[c4+3]=fmaf(coef,k[c4+3],W[c4+3]); b3=fmaf(W[c4+3],q[c4+3],b3);
      }
      const float z = xhalf_sum((b0+b1)+(b2+b3));
      if (!p) zrow0[(size_t)t*ROWP_ + r] = z;   // dead q-slot
    }
    asm volatile("s_waitcnt vmcnt(0)" ::: "memory");
  }
}

// ---------------- rec scan ----------------
// Serial chain: h -> exp -> ebuf write -> 4x broadcast b128 read -> dot2
// (4-deep) -> permlane combine -> rcp -> fma -> h. The h-independent R
// delta-update + staged k-loads fill the ebuf LDS round trip. All other
// combines (dot1, Ssum, dot2) are VALU permlane ops.
__global__ __launch_bounds__(64,1) void rec_scan(const float* __restrict__ qkvT,
                                                 float* __restrict__ hs){
  const int pair = blockIdx.x;
  const int lane = threadIdx.x;
  const int r = lane & 31, p = lane >> 5;
  const int b = pair >> 3, hh = pair & 7;
  const float* gbase = qkvT + (size_t)pair*S_*ROWP_;

  __shared__ __align__(16) float Lrk[2][CH2_][DH_];
  __shared__ __align__(16) float Lrv[2][CH2_][DH_];
  __shared__ __align__(16) float Lz [2][CH2_][DH_];
  __shared__ __align__(16) float Lb [2][CH2_][4];
  __shared__ __align__(16) float ebuf[2][DH_];

  float R[16];
  #pragma unroll
  for (int i=0;i<16;i++) R[i]=0.f;
  float h = 0.f;

  stage_plane32(gbase, 3*DH_, &Lrk[0][0][0], lane);
  stage_plane32(gbase, 4*DH_, &Lrv[0][0][0], lane);
  stage_plane32(gbase, 0,     &Lz [0][0][0], lane);
  stage_beta32 (gbase,        &Lb [0][0][0], lane);
  asm volatile("s_waitcnt vmcnt(0)" ::: "memory");

  for (int c = 0; c < NC2_; ++c){
    const int bi = c & 1;
    if (c+1 < NC2_){
      const float* gnext = gbase + (size_t)(c+1)*CH2_*ROWP_;
      stage_plane32(gnext, 3*DH_, &Lrk[bi^1][0][0], lane);
      stage_plane32(gnext, 4*DH_, &Lrv[bi^1][0][0], lane);
      stage_plane32(gnext, 0,     &Lz [bi^1][0][0], lane);
      stage_beta32 (gnext,        &Lb [bi^1][0][0], lane);
    }
    const int s0 = c*CH2_;
    #pragma unroll 4
    for (int t = 0; t < CH2_; ++t){
      // ---- h-chain head: publish e = exp(h_prev)  (h valid in both halves)
      const float e = __expf(h);
      if (!p) ebuf[t&1][r] = e;

      float k[16];
      #pragma unroll
      for (int j=0;j<4;j++)
        *(float4*)&k[4*j] = *(const float4*)&Lrk[bi][t][p*16 + 4*j];
      const float vv = Lrv[bi][t][r];
      const float zz = Lz [bi][t][r];
      const float bb = Lb [bi][t][1];

      // ---- R delta update (h-independent; covers the ebuf round trip)
      float a0=0.f,a1=0.f,a2=0.f,a3=0.f;
      #pragma unroll
      for (int c4=0;c4<16;c4+=4){
        a0=fmaf(R[c4+0],k[c4+0],a0); a1=fmaf(R[c4+1],k[c4+1],a1);
        a2=fmaf(R[c4+2],k[c4+2],a2); a3=fmaf(R[c4+3],k[c4+3],a3);
      }
      const float dot1 = xhalf_sum((a0+a1)+(a2+a3));
      const float coef = bb*(vv - dot1);
      #pragma unroll
      for (int c4=0;c4<16;c4+=4){
        R[c4+0]=fmaf(coef,k[c4+0],R[c4+0]); R[c4+1]=fmaf(coef,k[c4+1],R[c4+1]);
        R[c4+2]=fmaf(coef,k[c4+2],R[c4+2]); R[c4+3]=fmaf(coef,k[c4+3],R[c4+3]);
      }

      // ---- read this half's 16 e-values (broadcast b128)
      float ev[16];
      #pragma unroll
      for (int j=0;j<4;j++)
        *(float4*)&ev[4*j] = *(const float4*)&ebuf[t&1][p*16 + 4*j];

      // Ssum: local 15-add tree + VALU cross-half combine (off dot2 chain)
      float t0=(ev[0]+ev[1])+(ev[2]+ev[3]),   t1=(ev[4]+ev[5])+(ev[6]+ev[7]);
      float t2=(ev[8]+ev[9])+(ev[10]+ev[11]), t3=(ev[12]+ev[13])+(ev[14]+ev[15]);
      const float Ss = xhalf_sum((t0+t1)+(t2+t3));

      // dot2 = R_new[r,:] . e
      float d0=0.f,d1=0.f,d2=0.f,d3=0.f;
      #pragma unroll
      for (int c4=0;c4<16;c4+=4){
        d0=fmaf(R[c4+0],ev[c4+0],d0); d1=fmaf(R[c4+1],ev[c4+1],d1);
        d2=fmaf(R[c4+2],ev[c4+2],d2); d3=fmaf(R[c4+3],ev[c4+3],d3);
      }
      const float dot2 = xhalf_sum((d0+d1)+(d2+d3));

      h = fmaf(dot2, __builtin_amdgcn_rcpf(Ss), zz);
      if (!p) hs[((size_t)(s0+t)*B_ + b)*D_ + hh*DH_ + r] = h;
    }
    asm volatile("s_waitcnt vmcnt(0)" ::: "memory");
  }
}

// ---------------- GEMM2 (C = hs . out_W^T + x) ----------------
__global__ __launch_bounds__(256) void gemm_out(const float* __restrict__ A,
                                                const float* __restrict__ Bm,
                                                const float* __restrict__ X,
                                                float* __restrict__ C,
                                                int M, int N, int K){
  const int BM=128, BN=128, BK=16;
  __shared__ float As[BK][BM+4];
  __shared__ float Bs[BK][BN+4];
  const int tid = threadIdx.x;
  const int m0 = blockIdx.y*BM, n0 = blockIdx.x*BN;
  const int tx = tid & 15, ty = tid >> 4;
  float acc[8][8];
  #pragma unroll
  for (int i=0;i<8;i++)
    #pragma unroll
    for (int j=0;j<8;j++) acc[i][j]=0.f;

  const int lrow = tid >> 2;
  const int lcol = (tid & 3) << 2;

  for (int k0=0;k0<K;k0+=BK){
    #pragma unroll
    for (int p=0;p<2;p++){
      const int row = lrow + p*64;
      const float4 va = *(const float4*)(A + (size_t)(m0+row)*K + k0 + lcol);
      As[lcol+0][row]=va.x; As[lcol+1][row]=va.y; As[lcol+2][row]=va.z; As[lcol+3][row]=va.w;
      const float4 vb = *(const float4*)(Bm + (size_t)(n0+row)*K + k0 + lcol);
      Bs[lcol+0][row]=vb.x; Bs[lcol+1][row]=vb.y; Bs[lcol+2][row]=vb.z; Bs[lcol+3][row]=vb.w;
    }
    __syncthreads();
    #pragma unroll
    for (int k=0;k<BK;k++){
      float a[8], bb[8];
      *(float4*)&a[0]  = *(const float4*)&As[k][ty*8];
      *(float4*)&a[4]  = *(const float4*)&As[k][ty*8+4];
      *(float4*)&bb[0] = *(const float4*)&Bs[k][tx*8];
      *(float4*)&bb[4] = *(const float4*)&Bs[k][tx*8+4];
      #pragma unroll
      for (int i=0;i<8;i++)
        #pragma unroll
        for (int j=0;j<8;j++) acc[i][j] = fmaf(a[i], bb[j], acc[i][j]);
    }
    __syncthreads();
  }
  #pragma unroll
  for (int i=0;i<8;i++){
    const size_t m = (size_t)(m0 + ty*8 + i);
    #pragma unroll
    for (int j=0;j<8;j+=4){
      const int n = n0 + tx*8 + j;
      float4 rr = make_float4(acc[i][j],acc[i][j+1],acc[i][j+2],acc[i][j+3]);
      const float4 xv = *(const float4*)(X + m*N + n);
      rr.x+=xv.x; rr.y+=xv.y; rr.z+=xv.z; rr.w+=xv.w;
      *(float4*)(C + m*N + n) = rr;
    }
  }
}

// ---------------- launcher ----------------
extern "C" void kernel_launch(void* const* d_in, const int* in_sizes, int n_in,
                              void* d_out, int out_size, void* d_ws, size_t ws_size,
                              hipStream_t stream) {
  const float* x      = (const float*)d_in[0];
  const float* slow_W = (const float*)d_in[1];
  const float* out_W  = (const float*)d_in[2];
  const float* ln_g   = (const float*)d_in[3];
  const float* ln_b   = (const float*)d_in[4];
  float* out = (float*)d_out;

  float* o    = out;                            // LN out in d_out (overwritten by GEMM2)
  float* qkvT = (float*)d_ws;                   // [256 pairs][512 s][164]  (86MB)
  float* hs   = qkvT + (size_t)B_*H_*S_*ROWP_;  // [SB][D] (16.8MB)

  ln_kernel<<<SB_, 256, 0, stream>>>(x, ln_g, ln_b, o);

  dim3 g1((E_ + 127)/128, SB_/128);             // (11, 128)
  gemm_qkvT<<<g1, 256, 0, stream>>>(o, slow_W, qkvT, SB_, E_, D_);

  act2_kernel<<<B_*H_*S_/8, 256, 0, stream>>>(qkvT);

  ff_scan<<<B_*H_, 64, 0, stream>>>(qkvT);
  rec_scan<<<B_*H_, 64, 0, stream>>>(qkvT, hs);

  dim3 g2(D_/128, SB_/128);                     // (2, 128)
  gemm_out<<<g2, 256, 0, stream>>>(hs, out_W, x, out, SB_, D_, D_);
}

// Round 8
// 444.935 us; speedup vs baseline: 1.3584x; 1.2263x over previous
//
#include <hip/hip_runtime.h>
#include <hip/hip_bf16.h>
#include <math.h>

// Problem constants (from reference)
#define S_   512
#define B_   32
#define D_   256
#define H_   8
#define DH_  32
#define E_   (H_*(5*DH_+2))   // 1296
#define SB_  (S_*B_)          // 16384
#define LN_EPSF 1e-5f

#define ROWP_ 164             // padded row stride (floats): 656B, 16B-aligned
#define CH2_  32              // scan chunk (steps)
#define NC2_  (S_/CH2_)       // 16 chunks
#define NPAD_ 1344            // slow_W rows padded to 21*64 (zero-filled tail)

typedef short  bf16x8 __attribute__((ext_vector_type(8)));   // 8 bf16 = 4 VGPR
typedef float  f32x4  __attribute__((ext_vector_type(4)));

// ---------------- cross-lane helpers ----------------
__device__ __forceinline__ float wave_sum64(float v){
  #pragma unroll
  for (int m = 32; m >= 1; m >>= 1) v += __shfl_xor(v, m, 64);
  return v;
}
__device__ __forceinline__ float gsum32(float v){
  #pragma unroll
  for (int m = 16; m >= 1; m >>= 1) v += __shfl_xor(v, m, 32);
  return v;
}
__device__ __forceinline__ float gmax32(float v){
  #pragma unroll
  for (int m = 16; m >= 1; m >>= 1) v = fmaxf(v, __shfl_xor(v, m, 32));
  return v;
}

// cross-half (lane r <-> lane r+32) SUM via v_permlane32_swap_b32 (VALU).
#if __has_builtin(__builtin_amdgcn_permlane32_swap)
typedef int v2i_ __attribute__((ext_vector_type(2)));
__device__ __forceinline__ float xhalf_sum(float x){
  v2i_ r = __builtin_amdgcn_permlane32_swap(__float_as_int(x), __float_as_int(x), false, false);
  return __int_as_float(r.x) + __int_as_float(r.y);
}
#else
__device__ __forceinline__ float xhalf_sum(float x){
  return x + __shfl_xor(x, 32, 64);
}
#endif

// ---------------- global->LDS DMA helpers ----------------
__device__ __forceinline__ void gl16(const float* g, float* l){
  __builtin_amdgcn_global_load_lds(
      (const __attribute__((address_space(1))) unsigned int*)g,
      (__attribute__((address_space(3))) unsigned int*)l, 16, 0, 0);
}
__device__ __forceinline__ void stage_plane32(const float* gb, int fieldOff,
                                              float* plane, int lane){
  const int tt = lane >> 3, dd = (lane & 7) << 2;
  #pragma unroll
  for (int i = 0; i < 4; i++)
    gl16(gb + (size_t)(8*i + tt)*ROWP_ + fieldOff + dd, plane + i*256);
}
__device__ __forceinline__ void stage_beta32(const float* gb, float* bpl, int lane){
  if (lane < CH2_) gl16(gb + (size_t)lane*ROWP_ + 5*DH_, bpl);
}

// ---------------- LayerNorm -> bf16 output ----------------
__global__ __launch_bounds__(256) void ln_kernel(const float* __restrict__ x,
                                                 const float* __restrict__ g,
                                                 const float* __restrict__ b,
                                                 __hip_bfloat16* __restrict__ o){
  __shared__ float sbuf[4];
  const int row = blockIdx.x, tid = threadIdx.x;
  const float v = x[(size_t)row*D_ + tid];
  float s = wave_sum64(v);
  if ((tid & 63) == 0) sbuf[tid >> 6] = s;
  __syncthreads();
  const float mu = (sbuf[0]+sbuf[1]+sbuf[2]+sbuf[3]) * (1.f/D_);
  __syncthreads();
  const float d = v - mu;
  float s2 = wave_sum64(d*d);
  if ((tid & 63) == 0) sbuf[tid >> 6] = s2;
  __syncthreads();
  const float var = (sbuf[0]+sbuf[1]+sbuf[2]+sbuf[3]) * (1.f/D_);
  const float rstd = rsqrtf(var + LN_EPSF);
  o[(size_t)row*D_ + tid] = __float2bfloat16(d*rstd*g[tid] + b[tid]);
}

// ---------------- weight conversions ----------------
__global__ __launch_bounds__(256) void cvt_w1(const float* __restrict__ W,
                                              __hip_bfloat16* __restrict__ o){
  const int r = blockIdx.x, c = threadIdx.x;
  const float v = (r < E_) ? W[(size_t)r*D_ + c] : 0.f;
  o[(size_t)r*D_ + c] = __float2bfloat16(v);
}
__global__ __launch_bounds__(256) void cvt_w2(const float* __restrict__ W,
                                              __hip_bfloat16* __restrict__ o){
  const size_t i = (size_t)blockIdx.x*256 + threadIdx.x;
  o[i] = __float2bfloat16(W[i]);
}

// ---------------- GEMM1 (MFMA bf16): qkvT scatter ----------------
// D = A.B^T: A = o_bf[16384][256], B = w1_bf[1344][256] (rows>=1296 zero).
// 4 waves/block, 64x64 tile, 2x2 16x16 subtiles/wave, K=256 unrolled.
// Fragments: lane l holds 8 k-contig bf16 of row (l&15), k-block (l>>4)*8.
// C/D: row=(l>>4)*4+reg, col=l&15   [m89-verified layout]
__global__ __launch_bounds__(256) void gemm1_mfma(const __hip_bfloat16* __restrict__ A,
                                                  const __hip_bfloat16* __restrict__ Bw,
                                                  float* __restrict__ qkvT){
  const int tid = threadIdx.x;
  const int w = tid >> 6, l = tid & 63;
  const int lr = l & 15, lk = (l >> 4) << 3;
  const int m0 = blockIdx.y*64 + (w>>1)*32;
  const int n0 = blockIdx.x*64 + (w&1)*32;

  const __hip_bfloat16* Ap = A  + (size_t)(m0+lr)*D_ + lk;
  const __hip_bfloat16* Bp = Bw + (size_t)(n0+lr)*D_ + lk;

  f32x4 acc00={0,0,0,0}, acc01={0,0,0,0}, acc10={0,0,0,0}, acc11={0,0,0,0};
  #pragma unroll
  for (int ks = 0; ks < 8; ++ks){
    const bf16x8 a0 = *(const bf16x8*)(Ap + ks*32);
    const bf16x8 a1 = *(const bf16x8*)(Ap + 16*D_ + ks*32);
    const bf16x8 b0 = *(const bf16x8*)(Bp + ks*32);
    const bf16x8 b1 = *(const bf16x8*)(Bp + 16*D_ + ks*32);
    acc00 = __builtin_amdgcn_mfma_f32_16x16x32_bf16(a0, b0, acc00, 0,0,0);
    acc01 = __builtin_amdgcn_mfma_f32_16x16x32_bf16(a0, b1, acc01, 0,0,0);
    acc10 = __builtin_amdgcn_mfma_f32_16x16x32_bf16(a1, b0, acc10, 0,0,0);
    acc11 = __builtin_amdgcn_mfma_f32_16x16x32_bf16(a1, b1, acc11, 0,0,0);
  }

  const int mrow = (l>>4)<<2;
  #pragma unroll
  for (int i=0;i<2;i++){
    #pragma unroll
    for (int j=0;j<2;j++){
      const f32x4 av = (i==0) ? (j==0?acc00:acc01) : (j==0?acc10:acc11);
      const int n = n0 + j*16 + lr;
      if (n < E_){
        const unsigned head = (unsigned)n / 162u;
        const unsigned jj   = (unsigned)n - head*162u;
        #pragma unroll
        for (int reg=0;reg<4;reg++){
          const int m = m0 + i*16 + mrow + reg;
          const int s = m >> 5, bq = m & 31;
          qkvT[((size_t)(bq*8u+head)*S_ + s)*ROWP_ + jj] = av[reg];
        }
      }
    }
  }
}

// ---------------- GEMM2 (MFMA bf16): out = hs_bf . out_W^T + x ----------------
__global__ __launch_bounds__(256) void gemm2_mfma(const __hip_bfloat16* __restrict__ A,
                                                  const __hip_bfloat16* __restrict__ Bw,
                                                  const float* __restrict__ X,
                                                  float* __restrict__ C){
  const int tid = threadIdx.x;
  const int w = tid >> 6, l = tid & 63;
  const int lr = l & 15, lk = (l >> 4) << 3;
  const int m0 = blockIdx.y*64 + (w>>1)*32;
  const int n0 = blockIdx.x*64 + (w&1)*32;

  const __hip_bfloat16* Ap = A  + (size_t)(m0+lr)*D_ + lk;
  const __hip_bfloat16* Bp = Bw + (size_t)(n0+lr)*D_ + lk;

  f32x4 acc00={0,0,0,0}, acc01={0,0,0,0}, acc10={0,0,0,0}, acc11={0,0,0,0};
  #pragma unroll
  for (int ks = 0; ks < 8; ++ks){
    const bf16x8 a0 = *(const bf16x8*)(Ap + ks*32);
    const bf16x8 a1 = *(const bf16x8*)(Ap + 16*D_ + ks*32);
    const bf16x8 b0 = *(const bf16x8*)(Bp + ks*32);
    const bf16x8 b1 = *(const bf16x8*)(Bp + 16*D_ + ks*32);
    acc00 = __builtin_amdgcn_mfma_f32_16x16x32_bf16(a0, b0, acc00, 0,0,0);
    acc01 = __builtin_amdgcn_mfma_f32_16x16x32_bf16(a0, b1, acc01, 0,0,0);
    acc10 = __builtin_amdgcn_mfma_f32_16x16x32_bf16(a1, b0, acc10, 0,0,0);
    acc11 = __builtin_amdgcn_mfma_f32_16x16x32_bf16(a1, b1, acc11, 0,0,0);
  }

  const int mrow = (l>>4)<<2;
  #pragma unroll
  for (int i=0;i<2;i++){
    #pragma unroll
    for (int j=0;j<2;j++){
      const f32x4 av = (i==0) ? (j==0?acc00:acc01) : (j==0?acc10:acc11);
      const int n = n0 + j*16 + lr;
      #pragma unroll
      for (int reg=0;reg<4;reg++){
        const size_t m = (size_t)(m0 + i*16 + mrow + reg);
        C[m*D_ + n] = av[reg] + X[m*D_ + n];
      }
    }
  }
}

// ---------------- activations, in-place on qkvT rows ----------------
__global__ __launch_bounds__(256) void act2_kernel(float* __restrict__ qkvT){
  const int row = blockIdx.x*8 + (threadIdx.x >> 5);
  const int i = threadIdx.x & 31;
  float* base = qkvT + (size_t)row*ROWP_;
  float qv  = base[i];
  float kv  = base[DH_ + i];
  float rkv = base[3*DH_ + i];
  qv = qv > 0.f ? qv + 1.f : __expf(qv);   // elu+1
  kv = kv > 0.f ? kv + 1.f : __expf(kv);
  const float qs = gsum32(qv);
  const float ks = gsum32(kv);
  const float rm = gmax32(rkv);
  const float re = __expf(rkv - rm);
  const float rs = gsum32(re);
  base[i]         = qv / qs;
  base[DH_ + i]   = kv / ks;
  base[3*DH_ + i] = re / rs;
  if (i < 2){
    const float bv = base[5*DH_ + i];
    base[5*DH_ + i] = 1.f/(1.f + __expf(-bv));
  }
}

// ---------------- ff scan (unchanged from R7) ----------------
__global__ __launch_bounds__(64,1) void ff_scan(float* __restrict__ qkvT){
  const int pair = blockIdx.x;
  const int lane = threadIdx.x;
  const int r = lane & 31, p = lane >> 5;
  float* gbase = qkvT + (size_t)pair*S_*ROWP_;

  __shared__ __align__(16) float Lq[2][CH2_][DH_];
  __shared__ __align__(16) float Lk[2][CH2_][DH_];
  __shared__ __align__(16) float Lv[2][CH2_][DH_];
  __shared__ __align__(16) float Lb[2][CH2_][4];

  float W[16];
  #pragma unroll
  for (int i=0;i<16;i++) W[i]=0.f;

  stage_plane32(gbase, 0,      &Lq[0][0][0], lane);
  stage_plane32(gbase, DH_,    &Lk[0][0][0], lane);
  stage_plane32(gbase, 2*DH_,  &Lv[0][0][0], lane);
  stage_beta32 (gbase,         &Lb[0][0][0], lane);
  asm volatile("s_waitcnt vmcnt(0)" ::: "memory");

  for (int c = 0; c < NC2_; ++c){
    const int bi = c & 1;
    if (c+1 < NC2_){
      const float* gnext = gbase + (size_t)(c+1)*CH2_*ROWP_;
      stage_plane32(gnext, 0,     &Lq[bi^1][0][0], lane);
      stage_plane32(gnext, DH_,   &Lk[bi^1][0][0], lane);
      stage_plane32(gnext, 2*DH_, &Lv[bi^1][0][0], lane);
      stage_beta32 (gnext,        &Lb[bi^1][0][0], lane);
    }
    float* zrow0 = gbase + (size_t)c*CH2_*ROWP_;
    #pragma unroll 4
    for (int t = 0; t < CH2_; ++t){
      float q[16], k[16];
      #pragma unroll
      for (int j=0;j<4;j++){
        *(float4*)&q[4*j] = *(const float4*)&Lq[bi][t][p*16 + 4*j];
        *(float4*)&k[4*j] = *(const float4*)&Lk[bi][t][p*16 + 4*j];
      }
      const float vv = Lv[bi][t][r];
      const float bb = Lb[bi][t][0];

      float a0=0.f,a1=0.f,a2=0.f,a3=0.f;
      #pragma unroll
      for (int c4=0;c4<16;c4+=4){
        a0=fmaf(W[c4+0],k[c4+0],a0); a1=fmaf(W[c4+1],k[c4+1],a1);
        a2=fmaf(W[c4+2],k[c4+2],a2); a3=fmaf(W[c4+3],k[c4+3],a3);
      }
      const float dot1 = xhalf_sum((a0+a1)+(a2+a3));
      const float coef = bb*(vv - dot1);

      float b0=0.f,b1=0.f,b2=0.f,b3=0.f;
      #pragma unroll
      for (int c4=0;c4<16;c4+=4){
        W[c4+0]=fmaf(coef,k[c4+0],W[c4+0]); b0=fmaf(W[c4+0],q[c4+0],b0);
        W[c4+1]=fmaf(coef,k[c4+1],W[c4+1]); b1=fmaf(W[c4+1],q[c4+1],b1);
        W[c4+2]=fmaf(coef,k[c4+2],W[c4+2]); b2=fmaf(W[c4+2],q[c4+2],b2);
        W[c4+3]=fmaf(coef,k[c4+3],W[c4+3]); b3=fmaf(W[c4+3],q[c4+3],b3);
      }
      const float z = xhalf_sum((b0+b1)+(b2+b3));
      if (!p) zrow0[(size_t)t*ROWP_ + r] = z;   // dead q-slot
    }
    asm volatile("s_waitcnt vmcnt(0)" ::: "memory");
  }
}

// ---------------- rec scan (R7 + bf16 h store) ----------------
__global__ __launch_bounds__(64,1) void rec_scan(const float* __restrict__ qkvT,
                                                 __hip_bfloat16* __restrict__ hsb){
  const int pair = blockIdx.x;
  const int lane = threadIdx.x;
  const int r = lane & 31, p = lane >> 5;
  const int b = pair >> 3, hh = pair & 7;
  const float* gbase = qkvT + (size_t)pair*S_*ROWP_;

  __shared__ __align__(16) float Lrk[2][CH2_][DH_];
  __shared__ __align__(16) float Lrv[2][CH2_][DH_];
  __shared__ __align__(16) float Lz [2][CH2_][DH_];
  __shared__ __align__(16) float Lb [2][CH2_][4];
  __shared__ __align__(16) float ebuf[2][DH_];

  float R[16];
  #pragma unroll
  for (int i=0;i<16;i++) R[i]=0.f;
  float h = 0.f;

  stage_plane32(gbase, 3*DH_, &Lrk[0][0][0], lane);
  stage_plane32(gbase, 4*DH_, &Lrv[0][0][0], lane);
  stage_plane32(gbase, 0,     &Lz [0][0][0], lane);
  stage_beta32 (gbase,        &Lb [0][0][0], lane);
  asm volatile("s_waitcnt vmcnt(0)" ::: "memory");

  for (int c = 0; c < NC2_; ++c){
    const int bi = c & 1;
    if (c+1 < NC2_){
      const float* gnext = gbase + (size_t)(c+1)*CH2_*ROWP_;
      stage_plane32(gnext, 3*DH_, &Lrk[bi^1][0][0], lane);
      stage_plane32(gnext, 4*DH_, &Lrv[bi^1][0][0], lane);
      stage_plane32(gnext, 0,     &Lz [bi^1][0][0], lane);
      stage_beta32 (gnext,        &Lb [bi^1][0][0], lane);
    }
    const int s0 = c*CH2_;
    #pragma unroll 4
    for (int t = 0; t < CH2_; ++t){
      const float e = __expf(h);
      if (!p) ebuf[t&1][r] = e;

      float k[16];
      #pragma unroll
      for (int j=0;j<4;j++)
        *(float4*)&k[4*j] = *(const float4*)&Lrk[bi][t][p*16 + 4*j];
      const float vv = Lrv[bi][t][r];
      const float zz = Lz [bi][t][r];
      const float bb = Lb [bi][t][1];

      float a0=0.f,a1=0.f,a2=0.f,a3=0.f;
      #pragma unroll
      for (int c4=0;c4<16;c4+=4){
        a0=fmaf(R[c4+0],k[c4+0],a0); a1=fmaf(R[c4+1],k[c4+1],a1);
        a2=fmaf(R[c4+2],k[c4+2],a2); a3=fmaf(R[c4+3],k[c4+3],a3);
      }
      const float dot1 = xhalf_sum((a0+a1)+(a2+a3));
      const float coef = bb*(vv - dot1);
      #pragma unroll
      for (int c4=0;c4<16;c4+=4){
        R[c4+0]=fmaf(coef,k[c4+0],R[c4+0]); R[c4+1]=fmaf(coef,k[c4+1],R[c4+1]);
        R[c4+2]=fmaf(coef,k[c4+2],R[c4+2]); R[c4+3]=fmaf(coef,k[c4+3],R[c4+3]);
      }

      float ev[16];
      #pragma unroll
      for (int j=0;j<4;j++)
        *(float4*)&ev[4*j] = *(const float4*)&ebuf[t&1][p*16 + 4*j];

      float t0=(ev[0]+ev[1])+(ev[2]+ev[3]),   t1=(ev[4]+ev[5])+(ev[6]+ev[7]);
      float t2=(ev[8]+ev[9])+(ev[10]+ev[11]), t3=(ev[12]+ev[13])+(ev[14]+ev[15]);
      const float Ss = xhalf_sum((t0+t1)+(t2+t3));

      float d0=0.f,d1=0.f,d2=0.f,d3=0.f;
      #pragma unroll
      for (int c4=0;c4<16;c4+=4){
        d0=fmaf(R[c4+0],ev[c4+0],d0); d1=fmaf(R[c4+1],ev[c4+1],d1);
        d2=fmaf(R[c4+2],ev[c4+2],d2); d3=fmaf(R[c4+3],ev[c4+3],d3);
      }
      const float dot2 = xhalf_sum((d0+d1)+(d2+d3));

      h = fmaf(dot2, __builtin_amdgcn_rcpf(Ss), zz);
      if (!p) hsb[((size_t)(s0+t)*B_ + b)*D_ + hh*DH_ + r] = __float2bfloat16(h);
    }
    asm volatile("s_waitcnt vmcnt(0)" ::: "memory");
  }
}

// ---------------- launcher ----------------
extern "C" void kernel_launch(void* const* d_in, const int* in_sizes, int n_in,
                              void* d_out, int out_size, void* d_ws, size_t ws_size,
                              hipStream_t stream) {
  const float* x      = (const float*)d_in[0];
  const float* slow_W = (const float*)d_in[1];
  const float* out_W  = (const float*)d_in[2];
  const float* ln_g   = (const float*)d_in[3];
  const float* ln_b   = (const float*)d_in[4];
  float* out = (float*)d_out;

  // ws layout (bytes): qkvT 86MB | obf/hsb (overlaid) 8.4MB | w1 0.69MB | w2 0.13MB
  float* qkvT = (float*)d_ws;                                   // [256][512][164]
  __hip_bfloat16* obf  = (__hip_bfloat16*)(qkvT + (size_t)B_*H_*S_*ROWP_);
  __hip_bfloat16* hsb  = obf;                                   // overlay: obf dead after gemm1
  __hip_bfloat16* w1bf = obf + (size_t)SB_*D_;                  // [1344][256]
  __hip_bfloat16* w2bf = w1bf + (size_t)NPAD_*D_;               // [256][256]

  cvt_w1<<<NPAD_, 256, 0, stream>>>(slow_W, w1bf);
  cvt_w2<<<D_, 256, 0, stream>>>(out_W, w2bf);
  ln_kernel<<<SB_, 256, 0, stream>>>(x, ln_g, ln_b, obf);

  dim3 g1(NPAD_/64, SB_/64);                   // (21, 256)
  gemm1_mfma<<<g1, 256, 0, stream>>>(obf, w1bf, qkvT);

  act2_kernel<<<B_*H_*S_/8, 256, 0, stream>>>(qkvT);

  ff_scan<<<B_*H_, 64, 0, stream>>>(qkvT);
  rec_scan<<<B_*H_, 64, 0, stream>>>(qkvT, hsb);

  dim3 g2(D_/64, SB_/64);                      // (4, 256)
  gemm2_mfma<<<g2, 256, 0, stream>>>(hsb, w2bf, x, out);
}

// Round 9
// 419.159 us; speedup vs baseline: 1.4419x; 1.0615x over previous
//
#include <hip/hip_runtime.h>
#include <hip/hip_bf16.h>
#include <math.h>

// Problem constants (from reference)
#define S_   512
#define B_   32
#define D_   256
#define H_   8
#define DH_  32
#define E_   (H_*(5*DH_+2))   // 1296
#define SB_  (S_*B_)          // 16384
#define LN_EPSF 1e-5f

#define ROWP_ 164             // padded row stride (floats): 656B, 16B-aligned
#define CH2_  32              // scan chunk (steps)
#define NC2_  (S_/CH2_)       // 16 chunks
#define NPAD_ 1344            // slow_W rows padded to 21*64 (zero-filled tail)

typedef short  bf16x8 __attribute__((ext_vector_type(8)));   // 8 bf16 = 4 VGPR
typedef float  f32x4  __attribute__((ext_vector_type(4)));

// ---------------- cross-lane helpers ----------------
__device__ __forceinline__ float wave_sum64(float v){
  #pragma unroll
  for (int m = 32; m >= 1; m >>= 1) v += __shfl_xor(v, m, 64);
  return v;
}
__device__ __forceinline__ float gsum32(float v){
  #pragma unroll
  for (int m = 16; m >= 1; m >>= 1) v += __shfl_xor(v, m, 32);
  return v;
}
__device__ __forceinline__ float gmax32(float v){
  #pragma unroll
  for (int m = 16; m >= 1; m >>= 1) v = fmaxf(v, __shfl_xor(v, m, 32));
  return v;
}

// cross-half (lane r <-> lane r+32) SUM via v_permlane32_swap_b32 (VALU).
#if __has_builtin(__builtin_amdgcn_permlane32_swap)
typedef int v2i_ __attribute__((ext_vector_type(2)));
__device__ __forceinline__ float xhalf_sum(float x){
  v2i_ r = __builtin_amdgcn_permlane32_swap(__float_as_int(x), __float_as_int(x), false, false);
  return __int_as_float(r.x) + __int_as_float(r.y);
}
#else
__device__ __forceinline__ float xhalf_sum(float x){
  return x + __shfl_xor(x, 32, 64);
}
#endif

// ---------------- global->LDS DMA helpers ----------------
__device__ __forceinline__ void gl16(const float* g, float* l){
  __builtin_amdgcn_global_load_lds(
      (const __attribute__((address_space(1))) unsigned int*)g,
      (__attribute__((address_space(3))) unsigned int*)l, 16, 0, 0);
}
__device__ __forceinline__ void stage_plane32(const float* gb, int fieldOff,
                                              float* plane, int lane){
  const int tt = lane >> 3, dd = (lane & 7) << 2;
  #pragma unroll
  for (int i = 0; i < 4; i++)
    gl16(gb + (size_t)(8*i + tt)*ROWP_ + fieldOff + dd, plane + i*256);
}
__device__ __forceinline__ void stage_beta32(const float* gb, float* bpl, int lane){
  if (lane < CH2_) gl16(gb + (size_t)lane*ROWP_ + 5*DH_, bpl);
}

// ---------------- LayerNorm -> bf16 output ----------------
__global__ __launch_bounds__(256) void ln_kernel(const float* __restrict__ x,
                                                 const float* __restrict__ g,
                                                 const float* __restrict__ b,
                                                 __hip_bfloat16* __restrict__ o){
  __shared__ float sbuf[4];
  const int row = blockIdx.x, tid = threadIdx.x;
  const float v = x[(size_t)row*D_ + tid];
  float s = wave_sum64(v);
  if ((tid & 63) == 0) sbuf[tid >> 6] = s;
  __syncthreads();
  const float mu = (sbuf[0]+sbuf[1]+sbuf[2]+sbuf[3]) * (1.f/D_);
  __syncthreads();
  const float d = v - mu;
  float s2 = wave_sum64(d*d);
  if ((tid & 63) == 0) sbuf[tid >> 6] = s2;
  __syncthreads();
  const float var = (sbuf[0]+sbuf[1]+sbuf[2]+sbuf[3]) * (1.f/D_);
  const float rstd = rsqrtf(var + LN_EPSF);
  o[(size_t)row*D_ + tid] = __float2bfloat16(d*rstd*g[tid] + b[tid]);
}

// ---------------- weight conversions ----------------
__global__ __launch_bounds__(256) void cvt_w1(const float* __restrict__ W,
                                              __hip_bfloat16* __restrict__ o){
  const int r = blockIdx.x, c = threadIdx.x;
  const float v = (r < E_) ? W[(size_t)r*D_ + c] : 0.f;
  o[(size_t)r*D_ + c] = __float2bfloat16(v);
}
__global__ __launch_bounds__(256) void cvt_w2(const float* __restrict__ W,
                                              __hip_bfloat16* __restrict__ o){
  const size_t i = (size_t)blockIdx.x*256 + threadIdx.x;
  o[i] = __float2bfloat16(W[i]);
}

// ---------------- GEMM1 (MFMA bf16): qkvT scatter ----------------
__global__ __launch_bounds__(256) void gemm1_mfma(const __hip_bfloat16* __restrict__ A,
                                                  const __hip_bfloat16* __restrict__ Bw,
                                                  float* __restrict__ qkvT){
  const int tid = threadIdx.x;
  const int w = tid >> 6, l = tid & 63;
  const int lr = l & 15, lk = (l >> 4) << 3;
  const int m0 = blockIdx.y*64 + (w>>1)*32;
  const int n0 = blockIdx.x*64 + (w&1)*32;

  const __hip_bfloat16* Ap = A  + (size_t)(m0+lr)*D_ + lk;
  const __hip_bfloat16* Bp = Bw + (size_t)(n0+lr)*D_ + lk;

  f32x4 acc00={0,0,0,0}, acc01={0,0,0,0}, acc10={0,0,0,0}, acc11={0,0,0,0};
  #pragma unroll
  for (int ks = 0; ks < 8; ++ks){
    const bf16x8 a0 = *(const bf16x8*)(Ap + ks*32);
    const bf16x8 a1 = *(const bf16x8*)(Ap + 16*D_ + ks*32);
    const bf16x8 b0 = *(const bf16x8*)(Bp + ks*32);
    const bf16x8 b1 = *(const bf16x8*)(Bp + 16*D_ + ks*32);
    acc00 = __builtin_amdgcn_mfma_f32_16x16x32_bf16(a0, b0, acc00, 0,0,0);
    acc01 = __builtin_amdgcn_mfma_f32_16x16x32_bf16(a0, b1, acc01, 0,0,0);
    acc10 = __builtin_amdgcn_mfma_f32_16x16x32_bf16(a1, b0, acc10, 0,0,0);
    acc11 = __builtin_amdgcn_mfma_f32_16x16x32_bf16(a1, b1, acc11, 0,0,0);
  }

  const int mrow = (l>>4)<<2;
  #pragma unroll
  for (int i=0;i<2;i++){
    #pragma unroll
    for (int j=0;j<2;j++){
      const f32x4 av = (i==0) ? (j==0?acc00:acc01) : (j==0?acc10:acc11);
      const int n = n0 + j*16 + lr;
      if (n < E_){
        const unsigned head = (unsigned)n / 162u;
        const unsigned jj   = (unsigned)n - head*162u;
        #pragma unroll
        for (int reg=0;reg<4;reg++){
          const int m = m0 + i*16 + mrow + reg;
          const int s = m >> 5, bq = m & 31;
          qkvT[((size_t)(bq*8u+head)*S_ + s)*ROWP_ + jj] = av[reg];
        }
      }
    }
  }
}

// ---------------- GEMM2 (MFMA bf16): out = hs_bf . out_W^T + x ----------------
__global__ __launch_bounds__(256) void gemm2_mfma(const __hip_bfloat16* __restrict__ A,
                                                  const __hip_bfloat16* __restrict__ Bw,
                                                  const float* __restrict__ X,
                                                  float* __restrict__ C){
  const int tid = threadIdx.x;
  const int w = tid >> 6, l = tid & 63;
  const int lr = l & 15, lk = (l >> 4) << 3;
  const int m0 = blockIdx.y*64 + (w>>1)*32;
  const int n0 = blockIdx.x*64 + (w&1)*32;

  const __hip_bfloat16* Ap = A  + (size_t)(m0+lr)*D_ + lk;
  const __hip_bfloat16* Bp = Bw + (size_t)(n0+lr)*D_ + lk;

  f32x4 acc00={0,0,0,0}, acc01={0,0,0,0}, acc10={0,0,0,0}, acc11={0,0,0,0};
  #pragma unroll
  for (int ks = 0; ks < 8; ++ks){
    const bf16x8 a0 = *(const bf16x8*)(Ap + ks*32);
    const bf16x8 a1 = *(const bf16x8*)(Ap + 16*D_ + ks*32);
    const bf16x8 b0 = *(const bf16x8*)(Bp + ks*32);
    const bf16x8 b1 = *(const bf16x8*)(Bp + 16*D_ + ks*32);
    acc00 = __builtin_amdgcn_mfma_f32_16x16x32_bf16(a0, b0, acc00, 0,0,0);
    acc01 = __builtin_amdgcn_mfma_f32_16x16x32_bf16(a0, b1, acc01, 0,0,0);
    acc10 = __builtin_amdgcn_mfma_f32_16x16x32_bf16(a1, b0, acc10, 0,0,0);
    acc11 = __builtin_amdgcn_mfma_f32_16x16x32_bf16(a1, b1, acc11, 0,0,0);
  }

  const int mrow = (l>>4)<<2;
  #pragma unroll
  for (int i=0;i<2;i++){
    #pragma unroll
    for (int j=0;j<2;j++){
      const f32x4 av = (i==0) ? (j==0?acc00:acc01) : (j==0?acc10:acc11);
      const int n = n0 + j*16 + lr;
      #pragma unroll
      for (int reg=0;reg<4;reg++){
        const size_t m = (size_t)(m0 + i*16 + mrow + reg);
        C[m*D_ + n] = av[reg] + X[m*D_ + n];
      }
    }
  }
}

// ---------------- activations, in-place on qkvT rows ----------------
__global__ __launch_bounds__(256) void act2_kernel(float* __restrict__ qkvT){
  const int row = blockIdx.x*8 + (threadIdx.x >> 5);
  const int i = threadIdx.x & 31;
  float* base = qkvT + (size_t)row*ROWP_;
  float qv  = base[i];
  float kv  = base[DH_ + i];
  float rkv = base[3*DH_ + i];
  qv = qv > 0.f ? qv + 1.f : __expf(qv);   // elu+1
  kv = kv > 0.f ? kv + 1.f : __expf(kv);
  const float qs = gsum32(qv);
  const float ks = gsum32(kv);
  const float rm = gmax32(rkv);
  const float re = __expf(rkv - rm);
  const float rs = gsum32(re);
  base[i]         = qv / qs;
  base[DH_ + i]   = kv / ks;
  base[3*DH_ + i] = re / rs;
  if (i < 2){
    const float bv = base[5*DH_ + i];
    base[5*DH_ + i] = 1.f/(1.f + __expf(-bv));
  }
}

// ---------------- fused scan: both chains in ONE wave ----------------
// 256 blocks x 64 lanes. Lane (r,p) owns cols p*16..p*16+15 of BOTH W row r
// (ff chain) and R row r (rec chain). The chains are independent except z,
// which passes in-register -> while the h-recursion waits on its ebuf LDS
// round trip / exp, the W-chain's ~100 cyc of independent VALU work issues.
// Body order exploits the in-order DS pipe: ebuf write FIRST, then all
// staged reads, then ff compute (covers the round trip), then rec.
__global__ __launch_bounds__(64,1) void scan_fused(const float* __restrict__ qkvT,
                                                   __hip_bfloat16* __restrict__ hsb){
  const int pair = blockIdx.x;
  const int lane = threadIdx.x;
  const int r = lane & 31, p = lane >> 5;
  const int b = pair >> 3, hh = pair & 7;
  const float* gbase = qkvT + (size_t)pair*S_*ROWP_;

  __shared__ __align__(16) float Lq [2][CH2_][DH_];
  __shared__ __align__(16) float Lk [2][CH2_][DH_];
  __shared__ __align__(16) float Lv [2][CH2_][DH_];
  __shared__ __align__(16) float Lrk[2][CH2_][DH_];
  __shared__ __align__(16) float Lrv[2][CH2_][DH_];
  __shared__ __align__(16) float Lb [2][CH2_][4];
  __shared__ __align__(16) float ebuf[2][DH_];

  float W[16], R[16];
  #pragma unroll
  for (int i=0;i<16;i++){ W[i]=0.f; R[i]=0.f; }
  float h = 0.f;

  stage_plane32(gbase, 0,      &Lq [0][0][0], lane);
  stage_plane32(gbase, DH_,    &Lk [0][0][0], lane);
  stage_plane32(gbase, 2*DH_,  &Lv [0][0][0], lane);
  stage_plane32(gbase, 3*DH_,  &Lrk[0][0][0], lane);
  stage_plane32(gbase, 4*DH_,  &Lrv[0][0][0], lane);
  stage_beta32 (gbase,         &Lb [0][0][0], lane);
  asm volatile("s_waitcnt vmcnt(0)" ::: "memory");

  for (int c = 0; c < NC2_; ++c){
    const int bi = c & 1;
    if (c+1 < NC2_){
      const float* gnext = gbase + (size_t)(c+1)*CH2_*ROWP_;
      stage_plane32(gnext, 0,      &Lq [bi^1][0][0], lane);
      stage_plane32(gnext, DH_,    &Lk [bi^1][0][0], lane);
      stage_plane32(gnext, 2*DH_,  &Lv [bi^1][0][0], lane);
      stage_plane32(gnext, 3*DH_,  &Lrk[bi^1][0][0], lane);
      stage_plane32(gnext, 4*DH_,  &Lrv[bi^1][0][0], lane);
      stage_beta32 (gnext,         &Lb [bi^1][0][0], lane);
    }
    const int s0 = c*CH2_;
    #pragma unroll 2
    for (int t = 0; t < CH2_; ++t){
      // ---- h-chain head: publish e = exp(h_prev) into the DS pipe FIRST
      const float e = __expf(h);
      if (!p) ebuf[t&1][r] = e;

      // ---- issue all staged reads (in-order DS pipe, behind the write)
      float q[16], k[16], rk[16];
      #pragma unroll
      for (int j=0;j<4;j++){
        *(float4*)&q[4*j]  = *(const float4*)&Lq [bi][t][p*16 + 4*j];
        *(float4*)&k[4*j]  = *(const float4*)&Lk [bi][t][p*16 + 4*j];
        *(float4*)&rk[4*j] = *(const float4*)&Lrk[bi][t][p*16 + 4*j];
      }
      const float vv  = Lv [bi][t][r];
      const float rvv = Lrv[bi][t][r];
      const float2 bet = *(const float2*)&Lb[bi][t][0];   // (beta, rbeta)

      // ---- ff chain: dot1 -> coef -> W update + z-dot
      float a0=0.f,a1=0.f,a2=0.f,a3=0.f;
      #pragma unroll
      for (int c4=0;c4<16;c4+=4){
        a0=fmaf(W[c4+0],k[c4+0],a0); a1=fmaf(W[c4+1],k[c4+1],a1);
        a2=fmaf(W[c4+2],k[c4+2],a2); a3=fmaf(W[c4+3],k[c4+3],a3);
      }
      const float dot1f = xhalf_sum((a0+a1)+(a2+a3));
      const float coeff = bet.x*(vv - dot1f);
      float b0=0.f,b1=0.f,b2=0.f,b3=0.f;
      #pragma unroll
      for (int c4=0;c4<16;c4+=4){
        W[c4+0]=fmaf(coeff,k[c4+0],W[c4+0]); b0=fmaf(W[c4+0],q[c4+0],b0);
        W[c4+1]=fmaf(coeff,k[c4+1],W[c4+1]); b1=fmaf(W[c4+1],q[c4+1],b1);
        W[c4+2]=fmaf(coeff,k[c4+2],W[c4+2]); b2=fmaf(W[c4+2],q[c4+2],b2);
        W[c4+3]=fmaf(coeff,k[c4+3],W[c4+3]); b3=fmaf(W[c4+3],q[c4+3],b3);
      }
      const float z = xhalf_sum((b0+b1)+(b2+b3));       // in-register handoff

      // ---- rec R delta update (h-independent)
      float c0=0.f,c1=0.f,c2=0.f,c3=0.f;
      #pragma unroll
      for (int c4=0;c4<16;c4+=4){
        c0=fmaf(R[c4+0],rk[c4+0],c0); c1=fmaf(R[c4+1],rk[c4+1],c1);
        c2=fmaf(R[c4+2],rk[c4+2],c2); c3=fmaf(R[c4+3],rk[c4+3],c3);
      }
      const float dot1r = xhalf_sum((c0+c1)+(c2+c3));
      const float coefr = bet.y*(rvv - dot1r);
      #pragma unroll
      for (int c4=0;c4<16;c4+=4){
        R[c4+0]=fmaf(coefr,rk[c4+0],R[c4+0]); R[c4+1]=fmaf(coefr,rk[c4+1],R[c4+1]);
        R[c4+2]=fmaf(coefr,rk[c4+2],R[c4+2]); R[c4+3]=fmaf(coefr,rk[c4+3],R[c4+3]);
      }

      // ---- read this half's 16 e-values (broadcast b128; write landed long ago)
      float ev[16];
      #pragma unroll
      for (int j=0;j<4;j++)
        *(float4*)&ev[4*j] = *(const float4*)&ebuf[t&1][p*16 + 4*j];

      float t0=(ev[0]+ev[1])+(ev[2]+ev[3]),   t1=(ev[4]+ev[5])+(ev[6]+ev[7]);
      float t2=(ev[8]+ev[9])+(ev[10]+ev[11]), t3=(ev[12]+ev[13])+(ev[14]+ev[15]);
      const float Ss = xhalf_sum((t0+t1)+(t2+t3));

      float d0=0.f,d1=0.f,d2=0.f,d3=0.f;
      #pragma unroll
      for (int c4=0;c4<16;c4+=4){
        d0=fmaf(R[c4+0],ev[c4+0],d0); d1=fmaf(R[c4+1],ev[c4+1],d1);
        d2=fmaf(R[c4+2],ev[c4+2],d2); d3=fmaf(R[c4+3],ev[c4+3],d3);
      }
      const float dot2 = xhalf_sum((d0+d1)+(d2+d3));

      h = fmaf(dot2, __builtin_amdgcn_rcpf(Ss), z);
      if (!p) hsb[((size_t)(s0+t)*B_ + b)*D_ + hh*DH_ + r] = __float2bfloat16(h);
    }
    asm volatile("s_waitcnt vmcnt(0)" ::: "memory");
  }
}

// ---------------- launcher ----------------
extern "C" void kernel_launch(void* const* d_in, const int* in_sizes, int n_in,
                              void* d_out, int out_size, void* d_ws, size_t ws_size,
                              hipStream_t stream) {
  const float* x      = (const float*)d_in[0];
  const float* slow_W = (const float*)d_in[1];
  const float* out_W  = (const float*)d_in[2];
  const float* ln_g   = (const float*)d_in[3];
  const float* ln_b   = (const float*)d_in[4];
  float* out = (float*)d_out;

  // ws layout: qkvT 86MB | obf/hsb (overlaid) 8.4MB | w1 0.69MB | w2 0.13MB
  float* qkvT = (float*)d_ws;                                   // [256][512][164]
  __hip_bfloat16* obf  = (__hip_bfloat16*)(qkvT + (size_t)B_*H_*S_*ROWP_);
  __hip_bfloat16* hsb  = obf;                                   // overlay: obf dead after gemm1
  __hip_bfloat16* w1bf = obf + (size_t)SB_*D_;                  // [1344][256]
  __hip_bfloat16* w2bf = w1bf + (size_t)NPAD_*D_;               // [256][256]

  cvt_w1<<<NPAD_, 256, 0, stream>>>(slow_W, w1bf);
  cvt_w2<<<D_, 256, 0, stream>>>(out_W, w2bf);
  ln_kernel<<<SB_, 256, 0, stream>>>(x, ln_g, ln_b, obf);

  dim3 g1(NPAD_/64, SB_/64);                   // (21, 256)
  gemm1_mfma<<<g1, 256, 0, stream>>>(obf, w1bf, qkvT);

  act2_kernel<<<B_*H_*S_/8, 256, 0, stream>>>(qkvT);

  scan_fused<<<B_*H_, 64, 0, stream>>>(qkvT, hsb);

  dim3 g2(D_/64, SB_/64);                      // (4, 256)
  gemm2_mfma<<<g2, 256, 0, stream>>>(hsb, w2bf, x, out);
}

// Round 10
// 374.512 us; speedup vs baseline: 1.6138x; 1.1192x over previous
//
#include <hip/hip_runtime.h>
#include <hip/hip_bf16.h>
#include <math.h>

// Problem constants (from reference)
#define S_   512
#define B_   32
#define D_   256
#define H_   8
#define DH_  32
#define E_   (H_*(5*DH_+2))   // 1296
#define SB_  (S_*B_)          // 16384
#define LN_EPSF 1e-5f

#define ROWP_ 164             // padded row stride (floats): 656B, 16B-aligned
#define NPAD_ 1344            // slow_W rows padded to 21*64 (zero-filled tail)

typedef short  bf16x8 __attribute__((ext_vector_type(8)));
typedef float  f32x4  __attribute__((ext_vector_type(4)));
typedef float  f32x2  __attribute__((ext_vector_type(2)));

// ---------------- cross-lane helpers ----------------
__device__ __forceinline__ float wave_sum64(float v){
  #pragma unroll
  for (int m = 32; m >= 1; m >>= 1) v += __shfl_xor(v, m, 64);
  return v;
}
__device__ __forceinline__ float gsum32(float v){
  #pragma unroll
  for (int m = 16; m >= 1; m >>= 1) v += __shfl_xor(v, m, 32);
  return v;
}
__device__ __forceinline__ float gmax32(float v){
  #pragma unroll
  for (int m = 16; m >= 1; m >>= 1) v = fmaxf(v, __shfl_xor(v, m, 32));
  return v;
}

// cross-half (lane r <-> lane r+32) SUM via v_permlane32_swap_b32 (VALU).
#if __has_builtin(__builtin_amdgcn_permlane32_swap)
typedef int v2i_ __attribute__((ext_vector_type(2)));
__device__ __forceinline__ float xhalf_sum(float x){
  v2i_ r = __builtin_amdgcn_permlane32_swap(__float_as_int(x), __float_as_int(x), false, false);
  return __int_as_float(r.x) + __int_as_float(r.y);
}
#else
__device__ __forceinline__ float xhalf_sum(float x){
  return x + __shfl_xor(x, 32, 64);
}
#endif

// ---- inline-asm global loads (SGPR base + VGPR byte-voffset + imm) ----
// asm cannot be sunk by the scheduler; early-clobber so dst never aliases addr.
#define GL4(dst, sb, vo, IMM) \
  asm volatile("global_load_dwordx4 %0, %1, %2 offset:" IMM \
               : "=&v"(dst) : "v"(vo), "s"(sb))
#define GL2(dst, sb, vo, IMM) \
  asm volatile("global_load_dwordx2 %0, %1, %2 offset:" IMM \
               : "=&v"(dst) : "v"(vo), "s"(sb))
#define GL1(dst, sb, vo, IMM) \
  asm volatile("global_load_dword %0, %1, %2 offset:" IMM \
               : "=&v"(dst) : "v"(vo), "s"(sb))

// ---------------- LayerNorm -> bf16 output ----------------
__global__ __launch_bounds__(256) void ln_kernel(const float* __restrict__ x,
                                                 const float* __restrict__ g,
                                                 const float* __restrict__ b,
                                                 __hip_bfloat16* __restrict__ o){
  __shared__ float sbuf[4];
  const int row = blockIdx.x, tid = threadIdx.x;
  const float v = x[(size_t)row*D_ + tid];
  float s = wave_sum64(v);
  if ((tid & 63) == 0) sbuf[tid >> 6] = s;
  __syncthreads();
  const float mu = (sbuf[0]+sbuf[1]+sbuf[2]+sbuf[3]) * (1.f/D_);
  __syncthreads();
  const float d = v - mu;
  float s2 = wave_sum64(d*d);
  if ((tid & 63) == 0) sbuf[tid >> 6] = s2;
  __syncthreads();
  const float var = (sbuf[0]+sbuf[1]+sbuf[2]+sbuf[3]) * (1.f/D_);
  const float rstd = rsqrtf(var + LN_EPSF);
  o[(size_t)row*D_ + tid] = __float2bfloat16(d*rstd*g[tid] + b[tid]);
}

// ---------------- weight conversions ----------------
__global__ __launch_bounds__(256) void cvt_w1(const float* __restrict__ W,
                                              __hip_bfloat16* __restrict__ o){
  const int r = blockIdx.x, c = threadIdx.x;
  const float v = (r < E_) ? W[(size_t)r*D_ + c] : 0.f;
  o[(size_t)r*D_ + c] = __float2bfloat16(v);
}
__global__ __launch_bounds__(256) void cvt_w2(const float* __restrict__ W,
                                              __hip_bfloat16* __restrict__ o){
  const size_t i = (size_t)blockIdx.x*256 + threadIdx.x;
  o[i] = __float2bfloat16(W[i]);
}

// ---------------- GEMM1 (MFMA bf16): qkvT scatter ----------------
__global__ __launch_bounds__(256) void gemm1_mfma(const __hip_bfloat16* __restrict__ A,
                                                  const __hip_bfloat16* __restrict__ Bw,
                                                  float* __restrict__ qkvT){
  const int tid = threadIdx.x;
  const int w = tid >> 6, l = tid & 63;
  const int lr = l & 15, lk = (l >> 4) << 3;
  const int m0 = blockIdx.y*64 + (w>>1)*32;
  const int n0 = blockIdx.x*64 + (w&1)*32;

  const __hip_bfloat16* Ap = A  + (size_t)(m0+lr)*D_ + lk;
  const __hip_bfloat16* Bp = Bw + (size_t)(n0+lr)*D_ + lk;

  f32x4 acc00={0,0,0,0}, acc01={0,0,0,0}, acc10={0,0,0,0}, acc11={0,0,0,0};
  #pragma unroll
  for (int ks = 0; ks < 8; ++ks){
    const bf16x8 a0 = *(const bf16x8*)(Ap + ks*32);
    const bf16x8 a1 = *(const bf16x8*)(Ap + 16*D_ + ks*32);
    const bf16x8 b0 = *(const bf16x8*)(Bp + ks*32);
    const bf16x8 b1 = *(const bf16x8*)(Bp + 16*D_ + ks*32);
    acc00 = __builtin_amdgcn_mfma_f32_16x16x32_bf16(a0, b0, acc00, 0,0,0);
    acc01 = __builtin_amdgcn_mfma_f32_16x16x32_bf16(a0, b1, acc01, 0,0,0);
    acc10 = __builtin_amdgcn_mfma_f32_16x16x32_bf16(a1, b0, acc10, 0,0,0);
    acc11 = __builtin_amdgcn_mfma_f32_16x16x32_bf16(a1, b1, acc11, 0,0,0);
  }

  const int mrow = (l>>4)<<2;
  #pragma unroll
  for (int i=0;i<2;i++){
    #pragma unroll
    for (int j=0;j<2;j++){
      const f32x4 av = (i==0) ? (j==0?acc00:acc01) : (j==0?acc10:acc11);
      const int n = n0 + j*16 + lr;
      if (n < E_){
        const unsigned head = (unsigned)n / 162u;
        const unsigned jj   = (unsigned)n - head*162u;
        #pragma unroll
        for (int reg=0;reg<4;reg++){
          const int m = m0 + i*16 + mrow + reg;
          const int s = m >> 5, bq = m & 31;
          qkvT[((size_t)(bq*8u+head)*S_ + s)*ROWP_ + jj] = av[reg];
        }
      }
    }
  }
}

// ---------------- GEMM2 (MFMA bf16): out = hs_bf . out_W^T + x ----------------
__global__ __launch_bounds__(256) void gemm2_mfma(const __hip_bfloat16* __restrict__ A,
                                                  const __hip_bfloat16* __restrict__ Bw,
                                                  const float* __restrict__ X,
                                                  float* __restrict__ C){
  const int tid = threadIdx.x;
  const int w = tid >> 6, l = tid & 63;
  const int lr = l & 15, lk = (l >> 4) << 3;
  const int m0 = blockIdx.y*64 + (w>>1)*32;
  const int n0 = blockIdx.x*64 + (w&1)*32;

  const __hip_bfloat16* Ap = A  + (size_t)(m0+lr)*D_ + lk;
  const __hip_bfloat16* Bp = Bw + (size_t)(n0+lr)*D_ + lk;

  f32x4 acc00={0,0,0,0}, acc01={0,0,0,0}, acc10={0,0,0,0}, acc11={0,0,0,0};
  #pragma unroll
  for (int ks = 0; ks < 8; ++ks){
    const bf16x8 a0 = *(const bf16x8*)(Ap + ks*32);
    const bf16x8 a1 = *(const bf16x8*)(Ap + 16*D_ + ks*32);
    const bf16x8 b0 = *(const bf16x8*)(Bp + ks*32);
    const bf16x8 b1 = *(const bf16x8*)(Bp + 16*D_ + ks*32);
    acc00 = __builtin_amdgcn_mfma_f32_16x16x32_bf16(a0, b0, acc00, 0,0,0);
    acc01 = __builtin_amdgcn_mfma_f32_16x16x32_bf16(a0, b1, acc01, 0,0,0);
    acc10 = __builtin_amdgcn_mfma_f32_16x16x32_bf16(a1, b0, acc10, 0,0,0);
    acc11 = __builtin_amdgcn_mfma_f32_16x16x32_bf16(a1, b1, acc11, 0,0,0);
  }

  const int mrow = (l>>4)<<2;
  #pragma unroll
  for (int i=0;i<2;i++){
    #pragma unroll
    for (int j=0;j<2;j++){
      const f32x4 av = (i==0) ? (j==0?acc00:acc01) : (j==0?acc10:acc11);
      const int n = n0 + j*16 + lr;
      #pragma unroll
      for (int reg=0;reg<4;reg++){
        const size_t m = (size_t)(m0 + i*16 + mrow + reg);
        C[m*D_ + n] = av[reg] + X[m*D_ + n];
      }
    }
  }
}

// ---------------- activations, in-place on qkvT rows ----------------
__global__ __launch_bounds__(256) void act2_kernel(float* __restrict__ qkvT){
  const int row = blockIdx.x*8 + (threadIdx.x >> 5);
  const int i = threadIdx.x & 31;
  float* base = qkvT + (size_t)row*ROWP_;
  float qv  = base[i];
  float kv  = base[DH_ + i];
  float rkv = base[3*DH_ + i];
  qv = qv > 0.f ? qv + 1.f : __expf(qv);   // elu+1
  kv = kv > 0.f ? kv + 1.f : __expf(kv);
  const float qs = gsum32(qv);
  const float ks = gsum32(kv);
  const float rm = gmax32(rkv);
  const float re = __expf(rkv - rm);
  const float rs = gsum32(re);
  base[i]         = qv / qs;
  base[DH_ + i]   = kv / ks;
  base[3*DH_ + i] = re / rs;
  if (i < 2){
    const float bv = base[5*DH_ + i];
    base[5*DH_ + i] = 1.f/(1.f + __expf(-bv));
  }
}

// ---------------- fused scan v2: register pipeline, LDS only for e ----------------
// 256 blocks x 64 lanes, 1 wave. Lane (r,p) owns cols p*16..p*16+15 of W row r
// and R row r. ALL step inputs arrive global->register via inline-asm loads
// (SGPR base + voffset + imm) double-buffered 2 steps deep with counted
// s_waitcnt vmcnt(16) (15 loads + 1 h-store in flight per step, oldest-first).
// LDS use per step: 1 e-write + 4 broadcast ds_read_b128, issued BEFORE the
// vmcnt wait so the DS round trip completes inside it.
// Per-step field byte offsets in a 656B row: q=0+p*64+16j, k=128+.., rk=384+..,
// v=256+4r, rv=512+4r, (beta,rbeta)=640.
#define SCAN_ISSUE(P, sbp)                                                    \
  { const float* sb_ = (sbp);                                                 \
    GL4(P##q0,  sb_, voP, "0");   GL4(P##q1,  sb_, voP, "16");                \
    GL4(P##q2,  sb_, voP, "32");  GL4(P##q3,  sb_, voP, "48");                \
    GL4(P##k0,  sb_, voP, "128"); GL4(P##k1,  sb_, voP, "144");               \
    GL4(P##k2,  sb_, voP, "160"); GL4(P##k3,  sb_, voP, "176");               \
    GL4(P##rk0, sb_, voP, "384"); GL4(P##rk1, sb_, voP, "400");               \
    GL4(P##rk2, sb_, voP, "416"); GL4(P##rk3, sb_, voP, "432");               \
    GL1(P##v,   sb_, voR, "256"); GL1(P##rv,  sb_, voR, "512");               \
    GL2(P##bb,  sb_, voZ, "640"); }

#define SCAN_BODY(P, tt)                                                      \
  {                                                                           \
    /* e-transpose into the DS pipe first (depends only on prev h) */         \
    const float e_ = __expf(h);                                               \
    ebuf[r] = e_;                                                             \
    f32x4 ev0 = *(const f32x4*)&ebuf[p16+0];                                  \
    f32x4 ev1 = *(const f32x4*)&ebuf[p16+4];                                  \
    f32x4 ev2 = *(const f32x4*)&ebuf[p16+8];                                  \
    f32x4 ev3 = *(const f32x4*)&ebuf[p16+12];                                 \
    /* wait for THIS step's input registers */                                \
    if ((tt) >= S_-2) { asm volatile("s_waitcnt vmcnt(0)" ::: "memory"); }    \
    else              { asm volatile("s_waitcnt vmcnt(16)" ::: "memory"); }   \
    __builtin_amdgcn_sched_barrier(0);                                        \
    float q_[16], k_[16], rk_[16];                                            \
    *(f32x4*)&q_[0]=P##q0;  *(f32x4*)&q_[4]=P##q1;                            \
    *(f32x4*)&q_[8]=P##q2;  *(f32x4*)&q_[12]=P##q3;                           \
    *(f32x4*)&k_[0]=P##k0;  *(f32x4*)&k_[4]=P##k1;                            \
    *(f32x4*)&k_[8]=P##k2;  *(f32x4*)&k_[12]=P##k3;                           \
    *(f32x4*)&rk_[0]=P##rk0; *(f32x4*)&rk_[4]=P##rk1;                         \
    *(f32x4*)&rk_[8]=P##rk2; *(f32x4*)&rk_[12]=P##rk3;                        \
    const float vv = P##v, rvv = P##rv;                                       \
    const float beta = P##bb.x, rbeta = P##bb.y;                              \
    /* ---- ff chain ---- */                                                  \
    float a0=0.f,a1=0.f,a2=0.f,a3=0.f;                                        \
    _Pragma("unroll")                                                         \
    for (int c4=0;c4<16;c4+=4){                                               \
      a0=fmaf(W[c4+0],k_[c4+0],a0); a1=fmaf(W[c4+1],k_[c4+1],a1);             \
      a2=fmaf(W[c4+2],k_[c4+2],a2); a3=fmaf(W[c4+3],k_[c4+3],a3);             \
    }                                                                         \
    const float dot1f = xhalf_sum((a0+a1)+(a2+a3));                           \
    const float coeff = beta*(vv - dot1f);                                    \
    float b0=0.f,b1=0.f,b2=0.f,b3=0.f;                                        \
    _Pragma("unroll")                                                         \
    for (int c4=0;c4<16;c4+=4){                                               \
      W[c4+0]=fmaf(coeff,k_[c4+0],W[c4+0]); b0=fmaf(W[c4+0],q_[c4+0],b0);     \
      W[c4+1]=fmaf(coeff,k_[c4+1],W[c4+1]); b1=fmaf(W[c4+1],q_[c4+1],b1);     \
      W[c4+2]=fmaf(coeff,k_[c4+2],W[c4+2]); b2=fmaf(W[c4+2],q_[c4+2],b2);     \
      W[c4+3]=fmaf(coeff,k_[c4+3],W[c4+3]); b3=fmaf(W[c4+3],q_[c4+3],b3);     \
    }                                                                         \
    const float z_ = xhalf_sum((b0+b1)+(b2+b3));                              \
    /* ---- rec R delta update (h-independent) ---- */                        \
    float c0=0.f,c1=0.f,c2=0.f,c3=0.f;                                        \
    _Pragma("unroll")                                                         \
    for (int c4=0;c4<16;c4+=4){                                               \
      c0=fmaf(R[c4+0],rk_[c4+0],c0); c1=fmaf(R[c4+1],rk_[c4+1],c1);           \
      c2=fmaf(R[c4+2],rk_[c4+2],c2); c3=fmaf(R[c4+3],rk_[c4+3],c3);           \
    }                                                                         \
    const float dot1r = xhalf_sum((c0+c1)+(c2+c3));                           \
    const float coefr = rbeta*(rvv - dot1r);                                  \
    _Pragma("unroll")                                                         \
    for (int c4=0;c4<16;c4+=4){                                               \
      R[c4+0]=fmaf(coefr,rk_[c4+0],R[c4+0]); R[c4+1]=fmaf(coefr,rk_[c4+1],R[c4+1]); \
      R[c4+2]=fmaf(coefr,rk_[c4+2],R[c4+2]); R[c4+3]=fmaf(coefr,rk_[c4+3],R[c4+3]); \
    }                                                                         \
    /* ---- softmax-dot from the transposed e (read issued long ago) ---- */  \
    float evv[16];                                                            \
    *(f32x4*)&evv[0]=ev0; *(f32x4*)&evv[4]=ev1;                               \
    *(f32x4*)&evv[8]=ev2; *(f32x4*)&evv[12]=ev3;                              \
    float t0=(evv[0]+evv[1])+(evv[2]+evv[3]),   t1=(evv[4]+evv[5])+(evv[6]+evv[7]); \
    float t2=(evv[8]+evv[9])+(evv[10]+evv[11]), t3=(evv[12]+evv[13])+(evv[14]+evv[15]); \
    const float Ss = xhalf_sum((t0+t1)+(t2+t3));                              \
    float d0=0.f,d1=0.f,d2=0.f,d3=0.f;                                        \
    _Pragma("unroll")                                                         \
    for (int c4=0;c4<16;c4+=4){                                               \
      d0=fmaf(R[c4+0],evv[c4+0],d0); d1=fmaf(R[c4+1],evv[c4+1],d1);           \
      d2=fmaf(R[c4+2],evv[c4+2],d2); d3=fmaf(R[c4+3],evv[c4+3],d3);           \
    }                                                                         \
    const float dot2 = xhalf_sum((d0+d1)+(d2+d3));                            \
    h = fmaf(dot2, __builtin_amdgcn_rcpf(Ss), z_);                            \
    hsb[(size_t)(tt)*(B_*D_) + hoff] = __float2bfloat16(h);                   \
    /* reissue this buffer for step tt+2 */                                   \
    if ((tt)+2 < S_) SCAN_ISSUE(P, gbase + (size_t)((tt)+2)*ROWP_);           \
  }

__global__ __launch_bounds__(64,1) void scan_fused2(const float* __restrict__ qkvT,
                                                    __hip_bfloat16* __restrict__ hsb){
  const int pair = blockIdx.x;
  const int lane = threadIdx.x;
  const int r = lane & 31, p = lane >> 5;
  const int p16 = p*16;
  const int b = pair >> 3, hh = pair & 7;
  const float* gbase = qkvT + (size_t)pair*S_*ROWP_;
  const size_t hoff = (size_t)b*D_ + hh*DH_ + r;   // + t*B_*D_ per step

  __shared__ __align__(16) float ebuf[DH_];

  const int voP = p*64;   // byte voffset for q/k/rk 16-col slices
  const int voR = r*4;    // byte voffset for v/rv
  const int voZ = 0;      // beta pair is row-uniform

  float W[16], R[16];
  #pragma unroll
  for (int i=0;i<16;i++){ W[i]=0.f; R[i]=0.f; }
  float h = 0.f;

  // double-buffer register sets A (even steps) / B (odd steps)
  f32x4 Aq0,Aq1,Aq2,Aq3, Ak0,Ak1,Ak2,Ak3, Ark0,Ark1,Ark2,Ark3;
  f32x2 Abb; float Av, Arv;
  f32x4 Bq0,Bq1,Bq2,Bq3, Bk0,Bk1,Bk2,Bk3, Brk0,Brk1,Brk2,Brk3;
  f32x2 Bbb; float Bv, Brv;

  SCAN_ISSUE(A, gbase);                 // step 0
  SCAN_ISSUE(B, gbase + ROWP_);         // step 1
  asm volatile("s_waitcnt vmcnt(15)" ::: "memory");   // step-0 regs ready
  __builtin_amdgcn_sched_barrier(0);

  for (int tc = 0; tc < S_; tc += 2){
    SCAN_BODY(A, tc);
    SCAN_BODY(B, tc+1);
  }
}

// ---------------- launcher ----------------
extern "C" void kernel_launch(void* const* d_in, const int* in_sizes, int n_in,
                              void* d_out, int out_size, void* d_ws, size_t ws_size,
                              hipStream_t stream) {
  const float* x      = (const float*)d_in[0];
  const float* slow_W = (const float*)d_in[1];
  const float* out_W  = (const float*)d_in[2];
  const float* ln_g   = (const float*)d_in[3];
  const float* ln_b   = (const float*)d_in[4];
  float* out = (float*)d_out;

  // ws layout: qkvT 86MB | obf/hsb (overlaid) 8.4MB | w1 0.69MB | w2 0.13MB
  float* qkvT = (float*)d_ws;                                   // [256][512][164]
  __hip_bfloat16* obf  = (__hip_bfloat16*)(qkvT + (size_t)B_*H_*S_*ROWP_);
  __hip_bfloat16* hsb  = obf;                                   // overlay: obf dead after gemm1
  __hip_bfloat16* w1bf = obf + (size_t)SB_*D_;                  // [1344][256]
  __hip_bfloat16* w2bf = w1bf + (size_t)NPAD_*D_;               // [256][256]

  cvt_w1<<<NPAD_, 256, 0, stream>>>(slow_W, w1bf);
  cvt_w2<<<D_, 256, 0, stream>>>(out_W, w2bf);
  ln_kernel<<<SB_, 256, 0, stream>>>(x, ln_g, ln_b, obf);

  dim3 g1(NPAD_/64, SB_/64);                   // (21, 256)
  gemm1_mfma<<<g1, 256, 0, stream>>>(obf, w1bf, qkvT);

  act2_kernel<<<B_*H_*S_/8, 256, 0, stream>>>(qkvT);

  scan_fused2<<<B_*H_, 64, 0, stream>>>(qkvT, hsb);

  dim3 g2(D_/64, SB_/64);                      // (4, 256)
  gemm2_mfma<<<g2, 256, 0, stream>>>(hsb, w2bf, x, out);
}

// Round 17
// 373.402 us; speedup vs baseline: 1.6186x; 1.0030x over previous
//
#include <hip/hip_runtime.h>
#include <hip/hip_bf16.h>
#include <math.h>

// Problem constants (from reference)
#define S_   512
#define B_   32
#define D_   256
#define H_   8
#define DH_  32
#define E_   (H_*(5*DH_+2))   // 1296
#define SB_  (S_*B_)          // 16384
#define LN_EPSF 1e-5f

#define ROWP_ 164             // padded row stride (floats): 656B, 16B-aligned
#define NPAD_ 1344            // slow_W rows padded to 21*64 (zero-filled tail)

typedef short  bf16x8 __attribute__((ext_vector_type(8)));
typedef float  f32x4  __attribute__((ext_vector_type(4)));
typedef float  f32x2  __attribute__((ext_vector_type(2)));

// ---------------- cross-lane helpers ----------------
__device__ __forceinline__ float wave_sum64(float v){
  #pragma unroll
  for (int m = 32; m >= 1; m >>= 1) v += __shfl_xor(v, m, 64);
  return v;
}
__device__ __forceinline__ float gsum32(float v){
  #pragma unroll
  for (int m = 16; m >= 1; m >>= 1) v += __shfl_xor(v, m, 32);
  return v;
}
__device__ __forceinline__ float gmax32(float v){
  #pragma unroll
  for (int m = 16; m >= 1; m >>= 1) v = fmaxf(v, __shfl_xor(v, m, 32));
  return v;
}

// cross-half (lane r <-> lane r+32) SUM via v_permlane32_swap_b32 (VALU).
#if __has_builtin(__builtin_amdgcn_permlane32_swap)
typedef int v2i_ __attribute__((ext_vector_type(2)));
__device__ __forceinline__ float xhalf_sum(float x){
  v2i_ r = __builtin_amdgcn_permlane32_swap(__float_as_int(x), __float_as_int(x), false, false);
  return __int_as_float(r.x) + __int_as_float(r.y);
}
#else
__device__ __forceinline__ float xhalf_sum(float x){
  return x + __shfl_xor(x, 32, 64);
}
#endif

// ---- inline-asm global loads (SGPR base + VGPR byte-voffset + imm) ----
// asm cannot be sunk by the scheduler; early-clobber so dst never aliases addr.
// NOTE: this "s"-saddr + 2-deep form is the PROVEN R10 configuration. Depth>2
// variants failed 6x (SIGABRT/NaN/wrong) — do not deepen this pipeline.
#define GL4(dst, sb, vo, IMM) \
  asm volatile("global_load_dwordx4 %0, %1, %2 offset:" IMM \
               : "=&v"(dst) : "v"(vo), "s"(sb))
#define GL2(dst, sb, vo, IMM) \
  asm volatile("global_load_dwordx2 %0, %1, %2 offset:" IMM \
               : "=&v"(dst) : "v"(vo), "s"(sb))
#define GL1(dst, sb, vo, IMM) \
  asm volatile("global_load_dword %0, %1, %2 offset:" IMM \
               : "=&v"(dst) : "v"(vo), "s"(sb))

// ---------------- LayerNorm -> bf16 output ----------------
__global__ __launch_bounds__(256) void ln_kernel(const float* __restrict__ x,
                                                 const float* __restrict__ g,
                                                 const float* __restrict__ b,
                                                 __hip_bfloat16* __restrict__ o){
  __shared__ float sbuf[4];
  const int row = blockIdx.x, tid = threadIdx.x;
  const float v = x[(size_t)row*D_ + tid];
  float s = wave_sum64(v);
  if ((tid & 63) == 0) sbuf[tid >> 6] = s;
  __syncthreads();
  const float mu = (sbuf[0]+sbuf[1]+sbuf[2]+sbuf[3]) * (1.f/D_);
  __syncthreads();
  const float d = v - mu;
  float s2 = wave_sum64(d*d);
  if ((tid & 63) == 0) sbuf[tid >> 6] = s2;
  __syncthreads();
  const float var = (sbuf[0]+sbuf[1]+sbuf[2]+sbuf[3]) * (1.f/D_);
  const float rstd = rsqrtf(var + LN_EPSF);
  o[(size_t)row*D_ + tid] = __float2bfloat16(d*rstd*g[tid] + b[tid]);
}

// ---------------- weight conversions (merged: one launch) ----------------
__global__ __launch_bounds__(256) void cvt_w(const float* __restrict__ W1,
                                             const float* __restrict__ W2,
                                             __hip_bfloat16* __restrict__ o1,
                                             __hip_bfloat16* __restrict__ o2){
  const int r = blockIdx.x, c = threadIdx.x;
  if (r < NPAD_){
    const float v = (r < E_) ? W1[(size_t)r*D_ + c] : 0.f;
    o1[(size_t)r*D_ + c] = __float2bfloat16(v);
  } else {
    const int r2 = r - NPAD_;
    o2[(size_t)r2*D_ + c] = __float2bfloat16(W2[(size_t)r2*D_ + c]);
  }
}

// ---------------- GEMM1 (MFMA bf16): qkvT scatter ----------------
__global__ __launch_bounds__(256) void gemm1_mfma(const __hip_bfloat16* __restrict__ A,
                                                  const __hip_bfloat16* __restrict__ Bw,
                                                  float* __restrict__ qkvT){
  const int tid = threadIdx.x;
  const int w = tid >> 6, l = tid & 63;
  const int lr = l & 15, lk = (l >> 4) << 3;
  const int m0 = blockIdx.y*64 + (w>>1)*32;
  const int n0 = blockIdx.x*64 + (w&1)*32;

  const __hip_bfloat16* Ap = A  + (size_t)(m0+lr)*D_ + lk;
  const __hip_bfloat16* Bp = Bw + (size_t)(n0+lr)*D_ + lk;

  f32x4 acc00={0,0,0,0}, acc01={0,0,0,0}, acc10={0,0,0,0}, acc11={0,0,0,0};
  #pragma unroll
  for (int ks = 0; ks < 8; ++ks){
    const bf16x8 a0 = *(const bf16x8*)(Ap + ks*32);
    const bf16x8 a1 = *(const bf16x8*)(Ap + 16*D_ + ks*32);
    const bf16x8 b0 = *(const bf16x8*)(Bp + ks*32);
    const bf16x8 b1 = *(const bf16x8*)(Bp + 16*D_ + ks*32);
    acc00 = __builtin_amdgcn_mfma_f32_16x16x32_bf16(a0, b0, acc00, 0,0,0);
    acc01 = __builtin_amdgcn_mfma_f32_16x16x32_bf16(a0, b1, acc01, 0,0,0);
    acc10 = __builtin_amdgcn_mfma_f32_16x16x32_bf16(a1, b0, acc10, 0,0,0);
    acc11 = __builtin_amdgcn_mfma_f32_16x16x32_bf16(a1, b1, acc11, 0,0,0);
  }

  const int mrow = (l>>4)<<2;
  #pragma unroll
  for (int i=0;i<2;i++){
    #pragma unroll
    for (int j=0;j<2;j++){
      const f32x4 av = (i==0) ? (j==0?acc00:acc01) : (j==0?acc10:acc11);
      const int n = n0 + j*16 + lr;
      if (n < E_){
        const unsigned head = (unsigned)n / 162u;
        const unsigned jj   = (unsigned)n - head*162u;
        #pragma unroll
        for (int reg=0;reg<4;reg++){
          const int m = m0 + i*16 + mrow + reg;
          const int s = m >> 5, bq = m & 31;
          qkvT[((size_t)(bq*8u+head)*S_ + s)*ROWP_ + jj] = av[reg];
        }
      }
    }
  }
}

// ---------------- GEMM2 (MFMA bf16): out = hs_bf . out_W^T + x ----------------
__global__ __launch_bounds__(256) void gemm2_mfma(const __hip_bfloat16* __restrict__ A,
                                                  const __hip_bfloat16* __restrict__ Bw,
                                                  const float* __restrict__ X,
                                                  float* __restrict__ C){
  const int tid = threadIdx.x;
  const int w = tid >> 6, l = tid & 63;
  const int lr = l & 15, lk = (l >> 4) << 3;
  const int m0 = blockIdx.y*64 + (w>>1)*32;
  const int n0 = blockIdx.x*64 + (w&1)*32;

  const __hip_bfloat16* Ap = A  + (size_t)(m0+lr)*D_ + lk;
  const __hip_bfloat16* Bp = Bw + (size_t)(n0+lr)*D_ + lk;

  f32x4 acc00={0,0,0,0}, acc01={0,0,0,0}, acc10={0,0,0,0}, acc11={0,0,0,0};
  #pragma unroll
  for (int ks = 0; ks < 8; ++ks){
    const bf16x8 a0 = *(const bf16x8*)(Ap + ks*32);
    const bf16x8 a1 = *(const bf16x8*)(Ap + 16*D_ + ks*32);
    const bf16x8 b0 = *(const bf16x8*)(Bp + ks*32);
    const bf16x8 b1 = *(const bf16x8*)(Bp + 16*D_ + ks*32);
    acc00 = __builtin_amdgcn_mfma_f32_16x16x32_bf16(a0, b0, acc00, 0,0,0);
    acc01 = __builtin_amdgcn_mfma_f32_16x16x32_bf16(a0, b1, acc01, 0,0,0);
    acc10 = __builtin_amdgcn_mfma_f32_16x16x32_bf16(a1, b0, acc10, 0,0,0);
    acc11 = __builtin_amdgcn_mfma_f32_16x16x32_bf16(a1, b1, acc11, 0,0,0);
  }

  const int mrow = (l>>4)<<2;
  #pragma unroll
  for (int i=0;i<2;i++){
    #pragma unroll
    for (int j=0;j<2;j++){
      const f32x4 av = (i==0) ? (j==0?acc00:acc01) : (j==0?acc10:acc11);
      const int n = n0 + j*16 + lr;
      #pragma unroll
      for (int reg=0;reg<4;reg++){
        const size_t m = (size_t)(m0 + i*16 + mrow + reg);
        C[m*D_ + n] = av[reg] + X[m*D_ + n];
      }
    }
  }
}

// ---------------- activations, in-place on qkvT rows ----------------
__global__ __launch_bounds__(256) void act2_kernel(float* __restrict__ qkvT){
  const int row = blockIdx.x*8 + (threadIdx.x >> 5);
  const int i = threadIdx.x & 31;
  float* base = qkvT + (size_t)row*ROWP_;
  float qv  = base[i];
  float kv  = base[DH_ + i];
  float rkv = base[3*DH_ + i];
  qv = qv > 0.f ? qv + 1.f : __expf(qv);   // elu+1
  kv = kv > 0.f ? kv + 1.f : __expf(kv);
  const float qs = gsum32(qv);
  const float ks = gsum32(kv);
  const float rm = gmax32(rkv);
  const float re = __expf(rkv - rm);
  const float rs = gsum32(re);
  base[i]         = qv / qs;
  base[DH_ + i]   = kv / ks;
  base[3*DH_ + i] = re / rs;
  if (i < 2){
    const float bv = base[5*DH_ + i];
    base[5*DH_ + i] = 1.f/(1.f + __expf(-bv));
  }
}

// ---------------- fused scan v2: register pipeline, LDS only for e ----------------
// PROVEN R10 kernel (374.5us total, scan 234us, absmax 0.0156). 2-deep
// register double-buffer, inline-asm loads, steady vmcnt(16) (= 15 loads +
// 1 h-store in flight; stores count toward vmcnt on gfx950 — validated by
// this kernel passing). DO NOT deepen: depths 3/4 failed 6x on this
// toolchain (SIGABRT / NaN / wrong values).
#define SCAN_ISSUE(P, sbp)                                                    \
  { const float* sb_ = (sbp);                                                 \
    GL4(P##q0,  sb_, voP, "0");   GL4(P##q1,  sb_, voP, "16");                \
    GL4(P##q2,  sb_, voP, "32");  GL4(P##q3,  sb_, voP, "48");                \
    GL4(P##k0,  sb_, voP, "128"); GL4(P##k1,  sb_, voP, "144");               \
    GL4(P##k2,  sb_, voP, "160"); GL4(P##k3,  sb_, voP, "176");               \
    GL4(P##rk0, sb_, voP, "384"); GL4(P##rk1, sb_, voP, "400");               \
    GL4(P##rk2, sb_, voP, "416"); GL4(P##rk3, sb_, voP, "432");               \
    GL1(P##v,   sb_, voR, "256"); GL1(P##rv,  sb_, voR, "512");               \
    GL2(P##bb,  sb_, voZ, "640"); }

#define SCAN_BODY(P, tt)                                                      \
  {                                                                           \
    /* e-transpose into the DS pipe first (depends only on prev h) */         \
    const float e_ = __expf(h);                                               \
    ebuf[r] = e_;                                                             \
    f32x4 ev0 = *(const f32x4*)&ebuf[p16+0];                                  \
    f32x4 ev1 = *(const f32x4*)&ebuf[p16+4];                                  \
    f32x4 ev2 = *(const f32x4*)&ebuf[p16+8];                                  \
    f32x4 ev3 = *(const f32x4*)&ebuf[p16+12];                                 \
    /* wait for THIS step's input registers */                                \
    if ((tt) >= S_-2) { asm volatile("s_waitcnt vmcnt(0)" ::: "memory"); }    \
    else              { asm volatile("s_waitcnt vmcnt(16)" ::: "memory"); }   \
    __builtin_amdgcn_sched_barrier(0);                                        \
    float q_[16], k_[16], rk_[16];                                            \
    *(f32x4*)&q_[0]=P##q0;  *(f32x4*)&q_[4]=P##q1;                            \
    *(f32x4*)&q_[8]=P##q2;  *(f32x4*)&q_[12]=P##q3;                           \
    *(f32x4*)&k_[0]=P##k0;  *(f32x4*)&k_[4]=P##k1;                            \
    *(f32x4*)&k_[8]=P##k2;  *(f32x4*)&k_[12]=P##k3;                           \
    *(f32x4*)&rk_[0]=P##rk0; *(f32x4*)&rk_[4]=P##rk1;                         \
    *(f32x4*)&rk_[8]=P##rk2; *(f32x4*)&rk_[12]=P##rk3;                        \
    const float vv = P##v, rvv = P##rv;                                       \
    const float beta = P##bb.x, rbeta = P##bb.y;                              \
    /* ---- ff chain ---- */                                                  \
    float a0=0.f,a1=0.f,a2=0.f,a3=0.f;                                        \
    _Pragma("unroll")                                                         \
    for (int c4=0;c4<16;c4+=4){                                               \
      a0=fmaf(W[c4+0],k_[c4+0],a0); a1=fmaf(W[c4+1],k_[c4+1],a1);             \
      a2=fmaf(W[c4+2],k_[c4+2],a2); a3=fmaf(W[c4+3],k_[c4+3],a3);             \
    }                                                                         \
    const float dot1f = xhalf_sum((a0+a1)+(a2+a3));                           \
    const float coeff = beta*(vv - dot1f);                                    \
    float b0=0.f,b1=0.f,b2=0.f,b3=0.f;                                        \
    _Pragma("unroll")                                                         \
    for (int c4=0;c4<16;c4+=4){                                               \
      W[c4+0]=fmaf(coeff,k_[c4+0],W[c4+0]); b0=fmaf(W[c4+0],q_[c4+0],b0);     \
      W[c4+1]=fmaf(coeff,k_[c4+1],W[c4+1]); b1=fmaf(W[c4+1],q_[c4+1],b1);     \
      W[c4+2]=fmaf(coeff,k_[c4+2],W[c4+2]); b2=fmaf(W[c4+2],q_[c4+2],b2);     \
      W[c4+3]=fmaf(coeff,k_[c4+3],W[c4+3]); b3=fmaf(W[c4+3],q_[c4+3],b3);     \
    }                                                                         \
    const float z_ = xhalf_sum((b0+b1)+(b2+b3));                              \
    /* ---- rec R delta update (h-independent) ---- */                        \
    float c0=0.f,c1=0.f,c2=0.f,c3=0.f;                                        \
    _Pragma("unroll")                                                         \
    for (int c4=0;c4<16;c4+=4){                                               \
      c0=fmaf(R[c4+0],rk_[c4+0],c0); c1=fmaf(R[c4+1],rk_[c4+1],c1);           \
      c2=fmaf(R[c4+2],rk_[c4+2],c2); c3=fmaf(R[c4+3],rk_[c4+3],c3);           \
    }                                                                         \
    const float dot1r = xhalf_sum((c0+c1)+(c2+c3));                           \
    const float coefr = rbeta*(rvv - dot1r);                                  \
    _Pragma("unroll")                                                         \
    for (int c4=0;c4<16;c4+=4){                                               \
      R[c4+0]=fmaf(coefr,rk_[c4+0],R[c4+0]); R[c4+1]=fmaf(coefr,rk_[c4+1],R[c4+1]); \
      R[c4+2]=fmaf(coefr,rk_[c4+2],R[c4+2]); R[c4+3]=fmaf(coefr,rk_[c4+3],R[c4+3]); \
    }                                                                         \
    /* ---- softmax-dot from the transposed e (read issued long ago) ---- */  \
    float evv[16];                                                            \
    *(f32x4*)&evv[0]=ev0; *(f32x4*)&evv[4]=ev1;                               \
    *(f32x4*)&evv[8]=ev2; *(f32x4*)&evv[12]=ev3;                              \
    float t0=(evv[0]+evv[1])+(evv[2]+evv[3]),   t1=(evv[4]+evv[5])+(evv[6]+evv[7]); \
    float t2=(evv[8]+evv[9])+(evv[10]+evv[11]), t3=(evv[12]+evv[13])+(evv[14]+evv[15]); \
    const float Ss = xhalf_sum((t0+t1)+(t2+t3));                              \
    float d0=0.f,d1=0.f,d2=0.f,d3=0.f;                                        \
    _Pragma("unroll")                                                         \
    for (int c4=0;c4<16;c4+=4){                                               \
      d0=fmaf(R[c4+0],evv[c4+0],d0); d1=fmaf(R[c4+1],evv[c4+1],d1);           \
      d2=fmaf(R[c4+2],evv[c4+2],d2); d3=fmaf(R[c4+3],evv[c4+3],d3);           \
    }                                                                         \
    const float dot2 = xhalf_sum((d0+d1)+(d2+d3));                            \
    h = fmaf(dot2, __builtin_amdgcn_rcpf(Ss), z_);                            \
    hsb[(size_t)(tt)*(B_*D_) + hoff] = __float2bfloat16(h);                   \
    /* reissue this buffer for step tt+2 */                                   \
    if ((tt)+2 < S_) SCAN_ISSUE(P, gbase + (size_t)((tt)+2)*ROWP_);           \
  }

__global__ __launch_bounds__(64,1) void scan_fused2(const float* __restrict__ qkvT,
                                                    __hip_bfloat16* __restrict__ hsb){
  const int pair = blockIdx.x;
  const int lane = threadIdx.x;
  const int r = lane & 31, p = lane >> 5;
  const int p16 = p*16;
  const int b = pair >> 3, hh = pair & 7;
  const float* gbase = qkvT + (size_t)pair*S_*ROWP_;
  const size_t hoff = (size_t)b*D_ + hh*DH_ + r;   // + t*B_*D_ per step

  __shared__ __align__(16) float ebuf[DH_];

  const int voP = p*64;   // byte voffset for q/k/rk 16-col slices
  const int voR = r*4;    // byte voffset for v/rv
  const int voZ = 0;      // beta pair is row-uniform

  float W[16], R[16];
  #pragma unroll
  for (int i=0;i<16;i++){ W[i]=0.f; R[i]=0.f; }
  float h = 0.f;

  // double-buffer register sets A (even steps) / B (odd steps)
  f32x4 Aq0,Aq1,Aq2,Aq3, Ak0,Ak1,Ak2,Ak3, Ark0,Ark1,Ark2,Ark3;
  f32x2 Abb; float Av, Arv;
  f32x4 Bq0,Bq1,Bq2,Bq3, Bk0,Bk1,Bk2,Bk3, Brk0,Brk1,Brk2,Brk3;
  f32x2 Bbb; float Bv, Brv;

  SCAN_ISSUE(A, gbase);                 // step 0
  SCAN_ISSUE(B, gbase + ROWP_);         // step 1
  asm volatile("s_waitcnt vmcnt(15)" ::: "memory");   // step-0 regs ready
  __builtin_amdgcn_sched_barrier(0);

  for (int tc = 0; tc < S_; tc += 2){
    SCAN_BODY(A, tc);
    SCAN_BODY(B, tc+1);
  }
}

// ---------------- launcher ----------------
extern "C" void kernel_launch(void* const* d_in, const int* in_sizes, int n_in,
                              void* d_out, int out_size, void* d_ws, size_t ws_size,
                              hipStream_t stream) {
  const float* x      = (const float*)d_in[0];
  const float* slow_W = (const float*)d_in[1];
  const float* out_W  = (const float*)d_in[2];
  const float* ln_g   = (const float*)d_in[3];
  const float* ln_b   = (const float*)d_in[4];
  float* out = (float*)d_out;

  // ws layout: qkvT 86MB | obf/hsb (overlaid) 8.4MB | w1 0.69MB | w2 0.13MB
  float* qkvT = (float*)d_ws;                                   // [256][512][164]
  __hip_bfloat16* obf  = (__hip_bfloat16*)(qkvT + (size_t)B_*H_*S_*ROWP_);
  __hip_bfloat16* hsb  = obf;                                   // overlay: obf dead after gemm1
  __hip_bfloat16* w1bf = obf + (size_t)SB_*D_;                  // [1344][256]
  __hip_bfloat16* w2bf = w1bf + (size_t)NPAD_*D_;               // [256][256]

  cvt_w<<<NPAD_ + D_, 256, 0, stream>>>(slow_W, out_W, w1bf, w2bf);
  ln_kernel<<<SB_, 256, 0, stream>>>(x, ln_g, ln_b, obf);

  dim3 g1(NPAD_/64, SB_/64);                   // (21, 256)
  gemm1_mfma<<<g1, 256, 0, stream>>>(obf, w1bf, qkvT);

  act2_kernel<<<B_*H_*S_/8, 256, 0, stream>>>(qkvT);

  scan_fused2<<<B_*H_, 64, 0, stream>>>(qkvT, hsb);

  dim3 g2(D_/64, SB_/64);                      // (4, 256)
  gemm2_mfma<<<g2, 256, 0, stream>>>(hsb, w2bf, x, out);
}

// Round 18
// 366.206 us; speedup vs baseline: 1.6504x; 1.0196x over previous
//
#include <hip/hip_runtime.h>
#include <hip/hip_bf16.h>
#include <math.h>

// Problem constants (from reference)
#define S_   512
#define B_   32
#define D_   256
#define H_   8
#define DH_  32
#define E_   (H_*(5*DH_+2))   // 1296
#define SB_  (S_*B_)          // 16384
#define LN_EPSF 1e-5f

#define ROWB_ 384             // compact row stride BYTES (324 used, 16B-aligned)
#define ROWS_ 192             // compact row stride in ushorts
#define NPAD_ 1344            // slow_W rows padded to 21*64 (zero-filled tail)

typedef short        bf16x8 __attribute__((ext_vector_type(8)));
typedef float        f32x4  __attribute__((ext_vector_type(4)));
typedef unsigned int u32x4  __attribute__((ext_vector_type(4)));

// ---------------- cross-lane helpers ----------------
__device__ __forceinline__ float wave_sum64(float v){
  #pragma unroll
  for (int m = 32; m >= 1; m >>= 1) v += __shfl_xor(v, m, 64);
  return v;
}
__device__ __forceinline__ float gsum32(float v){
  #pragma unroll
  for (int m = 16; m >= 1; m >>= 1) v += __shfl_xor(v, m, 32);
  return v;
}
__device__ __forceinline__ float gmax32(float v){
  #pragma unroll
  for (int m = 16; m >= 1; m >>= 1) v = fmaxf(v, __shfl_xor(v, m, 32));
  return v;
}

// cross-half (lane r <-> lane r+32) SUM via v_permlane32_swap_b32 (VALU).
#if __has_builtin(__builtin_amdgcn_permlane32_swap)
typedef int v2i_ __attribute__((ext_vector_type(2)));
__device__ __forceinline__ float xhalf_sum(float x){
  v2i_ r = __builtin_amdgcn_permlane32_swap(__float_as_int(x), __float_as_int(x), false, false);
  return __int_as_float(r.x) + __int_as_float(r.y);
}
#else
__device__ __forceinline__ float xhalf_sum(float x){
  return x + __shfl_xor(x, 32, 64);
}
#endif

// bf16 helpers
__device__ __forceinline__ float bfl(unsigned u){ return __int_as_float((int)(u << 16)); }
__device__ __forceinline__ float bfh(unsigned u){ return __int_as_float((int)(u & 0xffff0000u)); }
__device__ __forceinline__ unsigned short bfb(float f){
  __hip_bfloat16 h = __float2bfloat16(f); return *(unsigned short*)&h;
}
__device__ __forceinline__ float bf2f(unsigned short u){
  return __int_as_float(((int)u) << 16);
}

// ---- inline-asm global loads (SGPR base + VGPR byte-voffset + imm) ----
// PROVEN R10 form (2-deep pipeline only — depth>2 failed 6x on this toolchain).
#define GL4(dst, sb, vo, IMM) \
  asm volatile("global_load_dwordx4 %0, %1, %2 offset:" IMM \
               : "=&v"(dst) : "v"(vo), "s"(sb))
#define GL1(dst, sb, vo, IMM) \
  asm volatile("global_load_dword %0, %1, %2 offset:" IMM \
               : "=&v"(dst) : "v"(vo), "s"(sb))

// ---------------- LayerNorm -> bf16 output ----------------
__global__ __launch_bounds__(256) void ln_kernel(const float* __restrict__ x,
                                                 const float* __restrict__ g,
                                                 const float* __restrict__ b,
                                                 __hip_bfloat16* __restrict__ o){
  __shared__ float sbuf[4];
  const int row = blockIdx.x, tid = threadIdx.x;
  const float v = x[(size_t)row*D_ + tid];
  float s = wave_sum64(v);
  if ((tid & 63) == 0) sbuf[tid >> 6] = s;
  __syncthreads();
  const float mu = (sbuf[0]+sbuf[1]+sbuf[2]+sbuf[3]) * (1.f/D_);
  __syncthreads();
  const float d = v - mu;
  float s2 = wave_sum64(d*d);
  if ((tid & 63) == 0) sbuf[tid >> 6] = s2;
  __syncthreads();
  const float var = (sbuf[0]+sbuf[1]+sbuf[2]+sbuf[3]) * (1.f/D_);
  const float rstd = rsqrtf(var + LN_EPSF);
  o[(size_t)row*D_ + tid] = __float2bfloat16(d*rstd*g[tid] + b[tid]);
}

// ---------------- weight conversions (merged: one launch) ----------------
__global__ __launch_bounds__(256) void cvt_w(const float* __restrict__ W1,
                                             const float* __restrict__ W2,
                                             __hip_bfloat16* __restrict__ o1,
                                             __hip_bfloat16* __restrict__ o2){
  const int r = blockIdx.x, c = threadIdx.x;
  if (r < NPAD_){
    const float v = (r < E_) ? W1[(size_t)r*D_ + c] : 0.f;
    o1[(size_t)r*D_ + c] = __float2bfloat16(v);
  } else {
    const int r2 = r - NPAD_;
    o2[(size_t)r2*D_ + c] = __float2bfloat16(W2[(size_t)r2*D_ + c]);
  }
}

// compact-row byte offset for head-local element jj (0..161):
//   q  jj[0,32)   -> 2*jj          (bytes   0..63)
//   k  jj[32,64)  -> 2*jj          (bytes  64..127)
//   v  jj[64,96)  -> 4*jj-64       (bytes 192..316, interleaved low)
//   rk jj[96,128) -> 2*jj-64       (bytes 128..191)
//   rv jj[128,160)-> 4*jj-318      (bytes 194..318, interleaved high)
//   beta/rbeta    -> 320/322
__device__ __forceinline__ int cmp_off(int jj){
  if (jj < 64)  return 2*jj;
  if (jj < 96)  return 4*jj - 64;
  if (jj < 128) return 2*jj - 64;
  if (jj < 160) return 4*jj - 318;
  return 320 + 2*(jj - 160);
}

// ---------------- GEMM1 (MFMA bf16) -> COMPACT bf16 qkvT scatter ----------------
__global__ __launch_bounds__(256) void gemm1_mfma(const __hip_bfloat16* __restrict__ A,
                                                  const __hip_bfloat16* __restrict__ Bw,
                                                  unsigned short* __restrict__ qc){
  const int tid = threadIdx.x;
  const int w = tid >> 6, l = tid & 63;
  const int lr = l & 15, lk = (l >> 4) << 3;
  const int m0 = blockIdx.y*64 + (w>>1)*32;
  const int n0 = blockIdx.x*64 + (w&1)*32;

  const __hip_bfloat16* Ap = A  + (size_t)(m0+lr)*D_ + lk;
  const __hip_bfloat16* Bp = Bw + (size_t)(n0+lr)*D_ + lk;

  f32x4 acc00={0,0,0,0}, acc01={0,0,0,0}, acc10={0,0,0,0}, acc11={0,0,0,0};
  #pragma unroll
  for (int ks = 0; ks < 8; ++ks){
    const bf16x8 a0 = *(const bf16x8*)(Ap + ks*32);
    const bf16x8 a1 = *(const bf16x8*)(Ap + 16*D_ + ks*32);
    const bf16x8 b0 = *(const bf16x8*)(Bp + ks*32);
    const bf16x8 b1 = *(const bf16x8*)(Bp + 16*D_ + ks*32);
    acc00 = __builtin_amdgcn_mfma_f32_16x16x32_bf16(a0, b0, acc00, 0,0,0);
    acc01 = __builtin_amdgcn_mfma_f32_16x16x32_bf16(a0, b1, acc01, 0,0,0);
    acc10 = __builtin_amdgcn_mfma_f32_16x16x32_bf16(a1, b0, acc10, 0,0,0);
    acc11 = __builtin_amdgcn_mfma_f32_16x16x32_bf16(a1, b1, acc11, 0,0,0);
  }

  const int mrow = (l>>4)<<2;
  #pragma unroll
  for (int i=0;i<2;i++){
    #pragma unroll
    for (int j=0;j<2;j++){
      const f32x4 av = (i==0) ? (j==0?acc00:acc01) : (j==0?acc10:acc11);
      const int n = n0 + j*16 + lr;
      if (n < E_){
        const unsigned head = (unsigned)n / 162u;
        const int jj = n - (int)head*162;
        const int off = cmp_off(jj);
        #pragma unroll
        for (int reg=0;reg<4;reg++){
          const int m = m0 + i*16 + mrow + reg;
          const int s = m >> 5, bq = m & 31;
          char* rowb = (char*)qc + ((size_t)(bq*8u+head)*S_ + s)*ROWB_;
          *(unsigned short*)(rowb + off) = bfb(av[reg]);
        }
      }
    }
  }
}

// ---------------- GEMM2 (MFMA bf16): out = hs_bf . out_W^T + x ----------------
__global__ __launch_bounds__(256) void gemm2_mfma(const __hip_bfloat16* __restrict__ A,
                                                  const __hip_bfloat16* __restrict__ Bw,
                                                  const float* __restrict__ X,
                                                  float* __restrict__ C){
  const int tid = threadIdx.x;
  const int w = tid >> 6, l = tid & 63;
  const int lr = l & 15, lk = (l >> 4) << 3;
  const int m0 = blockIdx.y*64 + (w>>1)*32;
  const int n0 = blockIdx.x*64 + (w&1)*32;

  const __hip_bfloat16* Ap = A  + (size_t)(m0+lr)*D_ + lk;
  const __hip_bfloat16* Bp = Bw + (size_t)(n0+lr)*D_ + lk;

  f32x4 acc00={0,0,0,0}, acc01={0,0,0,0}, acc10={0,0,0,0}, acc11={0,0,0,0};
  #pragma unroll
  for (int ks = 0; ks < 8; ++ks){
    const bf16x8 a0 = *(const bf16x8*)(Ap + ks*32);
    const bf16x8 a1 = *(const bf16x8*)(Ap + 16*D_ + ks*32);
    const bf16x8 b0 = *(const bf16x8*)(Bp + ks*32);
    const bf16x8 b1 = *(const bf16x8*)(Bp + 16*D_ + ks*32);
    acc00 = __builtin_amdgcn_mfma_f32_16x16x32_bf16(a0, b0, acc00, 0,0,0);
    acc01 = __builtin_amdgcn_mfma_f32_16x16x32_bf16(a0, b1, acc01, 0,0,0);
    acc10 = __builtin_amdgcn_mfma_f32_16x16x32_bf16(a1, b0, acc10, 0,0,0);
    acc11 = __builtin_amdgcn_mfma_f32_16x16x32_bf16(a1, b1, acc11, 0,0,0);
  }

  const int mrow = (l>>4)<<2;
  #pragma unroll
  for (int i=0;i<2;i++){
    #pragma unroll
    for (int j=0;j<2;j++){
      const f32x4 av = (i==0) ? (j==0?acc00:acc01) : (j==0?acc10:acc11);
      const int n = n0 + j*16 + lr;
      #pragma unroll
      for (int reg=0;reg<4;reg++){
        const size_t m = (size_t)(m0 + i*16 + mrow + reg);
        C[m*D_ + n] = av[reg] + X[m*D_ + n];
      }
    }
  }
}

// ---------------- act4: activations in-place on COMPACT bf16 rows ----------------
// Same-type (ushort) in-place read->compute->write at identical offsets:
// aliasing is respected by the compiler (same TBAA type), like proven act2.
__global__ __launch_bounds__(256) void act4_kernel(unsigned short* __restrict__ qc){
  const int row = blockIdx.x*8 + (threadIdx.x >> 5);
  const int i = threadIdx.x & 31;
  unsigned short* base = qc + (size_t)row*ROWS_;
  float qv  = bf2f(base[i]);
  float kv  = bf2f(base[32 + i]);
  float rkv = bf2f(base[64 + i]);
  qv = qv > 0.f ? qv + 1.f : __expf(qv);   // elu+1
  kv = kv > 0.f ? kv + 1.f : __expf(kv);
  const float qs = gsum32(qv);
  const float ks = gsum32(kv);
  const float rm = gmax32(rkv);
  const float re = __expf(rkv - rm);
  const float rs = gsum32(re);
  base[i]      = bfb(qv / qs);
  base[32 + i] = bfb(kv / ks);
  base[64 + i] = bfb(re / rs);
  if (i < 2){
    const float bv = bf2f(base[160 + i]);
    base[160 + i] = bfb(1.f/(1.f + __expf(-bv)));
  }
}

// ---------------- fused scan: 2-deep bf16 register pipeline ----------------
// PROVEN R10 skeleton (2-deep double-buffer, counted vmcnt; stores count
// toward vmcnt on gfx950 — validated by R10 at vmcnt(16)=15 loads+1 store).
// Inputs are compact bf16 rows: 8 VMEM/step (6 dwordx4 + 2 dword) + unpack.
// Steady wait = 1 newer body in flight = 8 loads + 1 store = vmcnt(9);
// prologue vmcnt(8); last two bodies vmcnt(0). DO NOT deepen past 2.
// Lane (r,p) byte offsets in a 384B row: q = p*32 + {0,16}; k = +{64,80};
// rk = +{128,144}; (v,rv) bf16 pair dword at 192+4r; (beta,rbeta) at 320.
#define SCAN_ISSUE(P, sbp)                                                    \
  { const char* sb_ = (sbp);                                                  \
    GL4(P##q0, sb_, voQ, "0");   GL4(P##q1, sb_, voQ, "16");                  \
    GL4(P##k0, sb_, voQ, "64");  GL4(P##k1, sb_, voQ, "80");                  \
    GL4(P##r0, sb_, voQ, "128"); GL4(P##r1, sb_, voQ, "144");                 \
    GL1(P##vr, sb_, voV, "192");                                              \
    GL1(P##bb, sb_, voZ, "320"); }

#define SCAN_BODY(P, tt)                                                      \
  {                                                                           \
    /* e-transpose into the DS pipe first (depends only on prev h) */         \
    const float e_ = __expf(h);                                               \
    ebuf[r] = e_;                                                             \
    f32x4 ev0 = *(const f32x4*)&ebuf[p16+0];                                  \
    f32x4 ev1 = *(const f32x4*)&ebuf[p16+4];                                  \
    f32x4 ev2 = *(const f32x4*)&ebuf[p16+8];                                  \
    f32x4 ev3 = *(const f32x4*)&ebuf[p16+12];                                 \
    /* wait for THIS step's input registers */                                \
    if ((tt) >= S_-2) { asm volatile("s_waitcnt vmcnt(0)" ::: "memory"); }    \
    else              { asm volatile("s_waitcnt vmcnt(9)" ::: "memory"); }    \
    __builtin_amdgcn_sched_barrier(0);                                        \
    /* unpack bf16 (1 VALU op per element) */                                 \
    float q_[16], k_[16], rk_[16];                                            \
    q_[0]=bfl(P##q0[0]);  q_[1]=bfh(P##q0[0]);  q_[2]=bfl(P##q0[1]);  q_[3]=bfh(P##q0[1]); \
    q_[4]=bfl(P##q0[2]);  q_[5]=bfh(P##q0[2]);  q_[6]=bfl(P##q0[3]);  q_[7]=bfh(P##q0[3]); \
    q_[8]=bfl(P##q1[0]);  q_[9]=bfh(P##q1[0]);  q_[10]=bfl(P##q1[1]); q_[11]=bfh(P##q1[1]);\
    q_[12]=bfl(P##q1[2]); q_[13]=bfh(P##q1[2]); q_[14]=bfl(P##q1[3]); q_[15]=bfh(P##q1[3]);\
    k_[0]=bfl(P##k0[0]);  k_[1]=bfh(P##k0[0]);  k_[2]=bfl(P##k0[1]);  k_[3]=bfh(P##k0[1]); \
    k_[4]=bfl(P##k0[2]);  k_[5]=bfh(P##k0[2]);  k_[6]=bfl(P##k0[3]);  k_[7]=bfh(P##k0[3]); \
    k_[8]=bfl(P##k1[0]);  k_[9]=bfh(P##k1[0]);  k_[10]=bfl(P##k1[1]); k_[11]=bfh(P##k1[1]);\
    k_[12]=bfl(P##k1[2]); k_[13]=bfh(P##k1[2]); k_[14]=bfl(P##k1[3]); k_[15]=bfh(P##k1[3]);\
    rk_[0]=bfl(P##r0[0]);  rk_[1]=bfh(P##r0[0]);  rk_[2]=bfl(P##r0[1]);  rk_[3]=bfh(P##r0[1]); \
    rk_[4]=bfl(P##r0[2]);  rk_[5]=bfh(P##r0[2]);  rk_[6]=bfl(P##r0[3]);  rk_[7]=bfh(P##r0[3]); \
    rk_[8]=bfl(P##r1[0]);  rk_[9]=bfh(P##r1[0]);  rk_[10]=bfl(P##r1[1]); rk_[11]=bfh(P##r1[1]);\
    rk_[12]=bfl(P##r1[2]); rk_[13]=bfh(P##r1[2]); rk_[14]=bfl(P##r1[3]); rk_[15]=bfh(P##r1[3]);\
    const float vv   = bfl(P##vr), rvv   = bfh(P##vr);                        \
    const float beta = bfl(P##bb), rbeta = bfh(P##bb);                        \
    /* ---- ff chain ---- */                                                  \
    float a0=0.f,a1=0.f,a2=0.f,a3=0.f;                                        \
    _Pragma("unroll")                                                         \
    for (int c4=0;c4<16;c4+=4){                                               \
      a0=fmaf(W[c4+0],k_[c4+0],a0); a1=fmaf(W[c4+1],k_[c4+1],a1);             \
      a2=fmaf(W[c4+2],k_[c4+2],a2); a3=fmaf(W[c4+3],k_[c4+3],a3);             \
    }                                                                         \
    const float dot1f = xhalf_sum((a0+a1)+(a2+a3));                           \
    const float coeff = beta*(vv - dot1f);                                    \
    float b0=0.f,b1=0.f,b2=0.f,b3=0.f;                                        \
    _Pragma("unroll")                                                         \
    for (int c4=0;c4<16;c4+=4){                                               \
      W[c4+0]=fmaf(coeff,k_[c4+0],W[c4+0]); b0=fmaf(W[c4+0],q_[c4+0],b0);     \
      W[c4+1]=fmaf(coeff,k_[c4+1],W[c4+1]); b1=fmaf(W[c4+1],q_[c4+1],b1);     \
      W[c4+2]=fmaf(coeff,k_[c4+2],W[c4+2]); b2=fmaf(W[c4+2],q_[c4+2],b2);     \
      W[c4+3]=fmaf(coeff,k_[c4+3],W[c4+3]); b3=fmaf(W[c4+3],q_[c4+3],b3);     \
    }                                                                         \
    const float z_ = xhalf_sum((b0+b1)+(b2+b3));                              \
    /* ---- rec R delta update (h-independent) ---- */                        \
    float c0=0.f,c1=0.f,c2=0.f,c3=0.f;                                        \
    _Pragma("unroll")                                                         \
    for (int c4=0;c4<16;c4+=4){                                               \
      c0=fmaf(R[c4+0],rk_[c4+0],c0); c1=fmaf(R[c4+1],rk_[c4+1],c1);           \
      c2=fmaf(R[c4+2],rk_[c4+2],c2); c3=fmaf(R[c4+3],rk_[c4+3],c3);           \
    }                                                                         \
    const float dot1r = xhalf_sum((c0+c1)+(c2+c3));                           \
    const float coefr = rbeta*(rvv - dot1r);                                  \
    _Pragma("unroll")                                                         \
    for (int c4=0;c4<16;c4+=4){                                               \
      R[c4+0]=fmaf(coefr,rk_[c4+0],R[c4+0]); R[c4+1]=fmaf(coefr,rk_[c4+1],R[c4+1]); \
      R[c4+2]=fmaf(coefr,rk_[c4+2],R[c4+2]); R[c4+3]=fmaf(coefr,rk_[c4+3],R[c4+3]); \
    }                                                                         \
    /* ---- softmax-dot from the transposed e (read issued long ago) ---- */  \
    float evv[16];                                                            \
    *(f32x4*)&evv[0]=ev0; *(f32x4*)&evv[4]=ev1;                               \
    *(f32x4*)&evv[8]=ev2; *(f32x4*)&evv[12]=ev3;                              \
    float t0=(evv[0]+evv[1])+(evv[2]+evv[3]),   t1=(evv[4]+evv[5])+(evv[6]+evv[7]); \
    float t2=(evv[8]+evv[9])+(evv[10]+evv[11]), t3=(evv[12]+evv[13])+(evv[14]+evv[15]); \
    const float Ss = xhalf_sum((t0+t1)+(t2+t3));                              \
    float d0=0.f,d1=0.f,d2=0.f,d3=0.f;                                        \
    _Pragma("unroll")                                                         \
    for (int c4=0;c4<16;c4+=4){                                               \
      d0=fmaf(R[c4+0],evv[c4+0],d0); d1=fmaf(R[c4+1],evv[c4+1],d1);           \
      d2=fmaf(R[c4+2],evv[c4+2],d2); d3=fmaf(R[c4+3],evv[c4+3],d3);           \
    }                                                                         \
    const float dot2 = xhalf_sum((d0+d1)+(d2+d3));                            \
    h = fmaf(dot2, __builtin_amdgcn_rcpf(Ss), z_);                            \
    hsb[(size_t)(tt)*(B_*D_) + hoff] = __float2bfloat16(h);                   \
    /* reissue this buffer for step tt+2 */                                   \
    if ((tt)+2 < S_) SCAN_ISSUE(P, gbase + (size_t)((tt)+2)*ROWB_);           \
  }

__global__ __launch_bounds__(64,1) void scan_fused2(const unsigned short* __restrict__ qc,
                                                    __hip_bfloat16* __restrict__ hsb){
  const int pair = blockIdx.x;
  const int lane = threadIdx.x;
  const int r = lane & 31, p = lane >> 5;
  const int p16 = p*16;
  const int b = pair >> 3, hh = pair & 7;
  const char* gbase = (const char*)qc + (size_t)pair*S_*ROWB_;
  const size_t hoff = (size_t)b*D_ + hh*DH_ + r;   // + t*B_*D_ per step

  __shared__ __align__(16) float ebuf[DH_];

  const int voQ = p*32;   // byte voffset for q/k/rk 16-col bf16 slices
  const int voV = r*4;    // byte voffset for the (v,rv) bf16 pair (base 192 in imm)
  const int voZ = 0;      // (beta,rbeta) row-uniform

  float W[16], R[16];
  #pragma unroll
  for (int i=0;i<16;i++){ W[i]=0.f; R[i]=0.f; }
  float h = 0.f;

  // 2-deep register buffer sets A (even steps) / B (odd steps), 26 VGPRs each
  u32x4 Aq0,Aq1, Ak0,Ak1, Ar0,Ar1; unsigned Avr, Abb;
  u32x4 Bq0,Bq1, Bk0,Bk1, Br0,Br1; unsigned Bvr, Bbb;

  SCAN_ISSUE(A, gbase);                 // step 0
  SCAN_ISSUE(B, gbase + ROWB_);         // step 1
  asm volatile("s_waitcnt vmcnt(8)" ::: "memory");   // step-0 regs ready
  __builtin_amdgcn_sched_barrier(0);

  for (int tc = 0; tc < S_; tc += 2){
    SCAN_BODY(A, tc);
    SCAN_BODY(B, tc+1);
  }
}

// ---------------- launcher ----------------
extern "C" void kernel_launch(void* const* d_in, const int* in_sizes, int n_in,
                              void* d_out, int out_size, void* d_ws, size_t ws_size,
                              hipStream_t stream) {
  const float* x      = (const float*)d_in[0];
  const float* slow_W = (const float*)d_in[1];
  const float* out_W  = (const float*)d_in[2];
  const float* ln_g   = (const float*)d_in[3];
  const float* ln_b   = (const float*)d_in[4];
  float* out = (float*)d_out;

  // ws layout: qc (compact bf16) 50.3MB | obf/hsb (overlaid) 8.4MB | w1 | w2
  unsigned short* qc  = (unsigned short*)d_ws;                  // [256][512][192 ushorts]
  __hip_bfloat16* obf = (__hip_bfloat16*)((char*)d_ws + (size_t)B_*H_*S_*ROWB_);
  __hip_bfloat16* hsb = obf;                                    // overlay: obf dead after gemm1
  __hip_bfloat16* w1bf = obf + (size_t)SB_*D_;                  // [1344][256]
  __hip_bfloat16* w2bf = w1bf + (size_t)NPAD_*D_;               // [256][256]

  cvt_w<<<NPAD_ + D_, 256, 0, stream>>>(slow_W, out_W, w1bf, w2bf);
  ln_kernel<<<SB_, 256, 0, stream>>>(x, ln_g, ln_b, obf);

  dim3 g1(NPAD_/64, SB_/64);                   // (21, 256)
  gemm1_mfma<<<g1, 256, 0, stream>>>(obf, w1bf, qc);

  act4_kernel<<<B_*H_*S_/8, 256, 0, stream>>>(qc);

  scan_fused2<<<B_*H_, 64, 0, stream>>>(qc, hsb);

  dim3 g2(D_/64, SB_/64);                      // (4, 256)
  gemm2_mfma<<<g2, 256, 0, stream>>>(hsb, w2bf, x, out);
}